// Round 2
// baseline (220.678 us; speedup 1.0000x reference)
//
#include <hip/hip_runtime.h>
#include <hip/hip_bf16.h>

// Problem: y = softmax_causal((x Wq^T)(x Wk^T)^T / 8) (x Wv^T)
// B=4, S=4096, D_EMBED=1024, D=64. Inputs fp32; compute in bf16 MFMA.

typedef short s16x8 __attribute__((ext_vector_type(8)));
typedef float f32x4 __attribute__((ext_vector_type(4)));

#define MFMA16(a, b, c) __builtin_amdgcn_mfma_f32_16x16x32_bf16(a, b, c, 0, 0, 0)

constexpr int SEQ = 4096;
constexpr int DE  = 1024;

// fp32 -> bf16 round-to-nearest-even
__device__ __forceinline__ short f2bf(float f) {
    union { float f; unsigned u; } v; v.f = f;
    unsigned r = (v.u + 0x7FFFu + ((v.u >> 16) & 1u)) >> 16;
    return (short)r;
}

// ---------------------------------------------------------------------------
// Kernel 0: convert W (fp32 [64][1024] x3) to concatenated bf16 [192][1024].
// Q-scale 0.125*log2(e) folded into Wq rows so attention can use exp2 directly.
__global__ __launch_bounds__(256) void k_convw(const float* __restrict__ Wq,
                                               const float* __restrict__ Wk,
                                               const float* __restrict__ Wv,
                                               short* __restrict__ Wb) {
    int i = (blockIdx.x * 256 + threadIdx.x) * 4;     // grid 192 -> covers 192*1024
    if (i >= 192 * 1024) return;
    int n = i >> 10, k = i & 1023;
    const float* src; float sc;
    if (n < 64)       { src = Wq + n * 1024;         sc = 0.18033688011112042f; }
    else if (n < 128) { src = Wk + (n - 64) * 1024;  sc = 1.0f; }
    else              { src = Wv + (n - 128) * 1024; sc = 1.0f; }
    float4 v = *(const float4*)(src + k);
    short4 o;
    o.x = f2bf(v.x * sc); o.y = f2bf(v.y * sc);
    o.z = f2bf(v.z * sc); o.w = f2bf(v.w * sc);
    *(short4*)(Wb + i) = o;
}

// ---------------------------------------------------------------------------
// Kernel 1: QKV projection. M=16384 rows (B*S), N=192 (Q|K|V), K=1024.
// LDS-free: A-frags loaded per-lane from x (fp32->bf16), B-frags from bf16 W (L1).
// Wave = 16 rows x 192 cols. Block = 4 waves = 64 rows. Grid = 256.
// Outputs: Qs [B*S][64] bf16 (scale folded), Ks [B*S][64] bf16, Vt [B][64][S] bf16.
__global__ __launch_bounds__(256) void k_proj(const float* __restrict__ x,
                                              const short* __restrict__ Wb,
                                              short* __restrict__ Qs,
                                              short* __restrict__ Ks,
                                              short* __restrict__ Vt) {
    int lane = threadIdx.x & 63, wv = threadIdx.x >> 6;
    int c = lane & 15, g = lane >> 4;
    int m0 = blockIdx.x * 64 + wv * 16;

    const float* xr = x + (size_t)(m0 + c) * DE;   // A-operand row = l&15

    f32x4 acc[12];
    const f32x4 z4 = {0.f, 0.f, 0.f, 0.f};
#pragma unroll
    for (int i = 0; i < 12; i++) acc[i] = z4;

    for (int k0 = 0; k0 < DE; k0 += 32) {
        float4 a0 = *(const float4*)(xr + k0 + g * 8);
        float4 a1 = *(const float4*)(xr + k0 + g * 8 + 4);
        s16x8 a;
        a[0] = f2bf(a0.x); a[1] = f2bf(a0.y); a[2] = f2bf(a0.z); a[3] = f2bf(a0.w);
        a[4] = f2bf(a1.x); a[5] = f2bf(a1.y); a[6] = f2bf(a1.z); a[7] = f2bf(a1.w);
        const short* wp = Wb + (size_t)c * DE + k0 + g * 8;
#pragma unroll
        for (int nf = 0; nf < 12; nf++) {
            s16x8 bfr = *(const s16x8*)(wp + (size_t)nf * 16 * DE);
            acc[nf] = MFMA16(a, bfr, acc[nf]);
        }
    }

    // Epilogue. C/D: col = nf*16 + (l&15), row = m0 + (l>>4)*4 + r.
#pragma unroll
    for (int nf = 0; nf < 12; nf++) {
        if (nf < 4) {
            int n = nf * 16 + c;
#pragma unroll
            for (int r = 0; r < 4; r++) {
                int m = m0 + g * 4 + r;
                Qs[(size_t)m * 64 + n] = f2bf(acc[nf][r]);
            }
        } else if (nf < 8) {
            int n = (nf - 4) * 16 + c;
#pragma unroll
            for (int r = 0; r < 4; r++) {
                int m = m0 + g * 4 + r;
                Ks[(size_t)m * 64 + n] = f2bf(acc[nf][r]);
            }
        } else {
            int d  = (nf - 8) * 16 + c;
            int m  = m0 + g * 4;          // 4 consecutive rows -> contiguous s
            int bt = m >> 12;             // batch
            int s0 = m & (SEQ - 1);
            short4 o;
            o.x = f2bf(acc[nf][0]); o.y = f2bf(acc[nf][1]);
            o.z = f2bf(acc[nf][2]); o.w = f2bf(acc[nf][3]);
            *(short4*)(Vt + ((size_t)(bt * 64 + d)) * SEQ + s0) = o;
        }
    }
}

// ---------------------------------------------------------------------------
// Kernel 2: causal flash attention. Block = 2 independent waves (no barriers),
// wave = 16 q-rows, KT = 64 kv per step. Grid = 512 in descending-work (LPT)
// order: j = 127 - bid/4, batch = bid & 3.
__global__ __launch_bounds__(128) void k_attn(const short* __restrict__ Qs,
                                              const short* __restrict__ Ks,
                                              const short* __restrict__ Vt,
                                              float* __restrict__ out) {
    __shared__ __align__(16) short plds[2][16][72];   // per-wave P buffer, pad->2-way

    int lane = threadIdx.x & 63, wv = threadIdx.x >> 6;
    int c = lane & 15, g = lane >> 4;
    int bid = blockIdx.x;
    int j  = 127 - (bid >> 2);
    int bt = bid & 3;
    int q0 = j * 32 + wv * 16;

    const short* Qb = Qs + (size_t)bt * SEQ * 64;
    const short* Kb = Ks + (size_t)bt * SEQ * 64;
    const short* Vb = Vt + (size_t)bt * 64 * SEQ;

    // Q fragments (A-operand): row = q0 + (l&15), k-chunks d=[0,32),[32,64)
    s16x8 qf0 = *(const s16x8*)(Qb + (size_t)(q0 + c) * 64 + g * 8);
    s16x8 qf1 = *(const s16x8*)(Qb + (size_t)(q0 + c) * 64 + 32 + g * 8);

    const f32x4 z4 = {0.f, 0.f, 0.f, 0.f};
    f32x4 o[4];
#pragma unroll
    for (int nf = 0; nf < 4; nf++) o[nf] = z4;
    float m[4], ll[4];
#pragma unroll
    for (int r = 0; r < 4; r++) { m[r] = -1e30f; ll[r] = 0.f; }

    const int kend = q0 + 16;                 // causal: k <= q_max = q0+15
    for (int k0 = 0; k0 < kend; k0 += 64) {
        // ---- S = Q K^T (scale & log2e pre-folded into Q) ----
        f32x4 sf[4];
#pragma unroll
        for (int kf = 0; kf < 4; kf++) {
            const short* kp = Kb + (size_t)(k0 + kf * 16 + c) * 64 + g * 8;
            s16x8 kb0 = *(const s16x8*)kp;
            s16x8 kb1 = *(const s16x8*)(kp + 32);
            f32x4 t = MFMA16(qf0, kb0, z4);
            sf[kf] = MFMA16(qf1, kb1, t);
        }
        // ---- causal mask (only near-diagonal tiles) ----
        if (k0 + 63 > q0) {
#pragma unroll
            for (int kf = 0; kf < 4; kf++) {
                int k = k0 + kf * 16 + c;
#pragma unroll
                for (int r = 0; r < 4; r++) {
                    int q = q0 + g * 4 + r;
                    if (k > q) sf[kf][r] = -3.0e38f;
                }
            }
        }
        // ---- online softmax (base-2) ----
        float mx[4];
#pragma unroll
        for (int r = 0; r < 4; r++)
            mx[r] = fmaxf(fmaxf(sf[0][r], sf[1][r]), fmaxf(sf[2][r], sf[3][r]));
#pragma unroll
        for (int off = 1; off < 16; off <<= 1) {
#pragma unroll
            for (int r = 0; r < 4; r++)
                mx[r] = fmaxf(mx[r], __shfl_xor(mx[r], off));
        }
        float sc[4];
#pragma unroll
        for (int r = 0; r < 4; r++) {
            float mn = fmaxf(m[r], mx[r]);
            sc[r] = __builtin_amdgcn_exp2f(m[r] - mn);
            m[r] = mn;
        }
#pragma unroll
        for (int kf = 0; kf < 4; kf++)
#pragma unroll
            for (int r = 0; r < 4; r++)
                sf[kf][r] = __builtin_amdgcn_exp2f(sf[kf][r] - m[r]);
        float sum[4];
#pragma unroll
        for (int r = 0; r < 4; r++)
            sum[r] = (sf[0][r] + sf[1][r]) + (sf[2][r] + sf[3][r]);
#pragma unroll
        for (int off = 1; off < 16; off <<= 1) {
#pragma unroll
            for (int r = 0; r < 4; r++)
                sum[r] += __shfl_xor(sum[r], off);
        }
#pragma unroll
        for (int r = 0; r < 4; r++) ll[r] = ll[r] * sc[r] + sum[r];
#pragma unroll
        for (int nf = 0; nf < 4; nf++)
#pragma unroll
            for (int r = 0; r < 4; r++) o[nf][r] *= sc[r];

        // ---- P -> bf16 via per-wave LDS round-trip (transpose to A-frag) ----
        asm volatile("s_waitcnt lgkmcnt(0)" ::: "memory");  // WAR vs prev PV reads
        __builtin_amdgcn_sched_barrier(0);
#pragma unroll
        for (int kf = 0; kf < 4; kf++)
#pragma unroll
            for (int r = 0; r < 4; r++)
                plds[wv][g * 4 + r][kf * 16 + c] = f2bf(sf[kf][r]);
        asm volatile("s_waitcnt lgkmcnt(0)" ::: "memory");  // writes visible to reads
        __builtin_amdgcn_sched_barrier(0);
        s16x8 pa0 = *(const s16x8*)&plds[wv][c][g * 8];
        s16x8 pa1 = *(const s16x8*)&plds[wv][c][32 + g * 8];

        // ---- O += P V  (B-frag from Vt: s-contiguous) ----
#pragma unroll
        for (int nf = 0; nf < 4; nf++) {
            const short* vp = Vb + (size_t)(nf * 16 + c) * SEQ + k0 + g * 8;
            s16x8 v0 = *(const s16x8*)vp;
            s16x8 v1 = *(const s16x8*)(vp + 32);
            o[nf] = MFMA16(pa0, v0, o[nf]);
            o[nf] = MFMA16(pa1, v1, o[nf]);
        }
    }

    // ---- epilogue: O / l, fp32 out [B][S][64] ----
#pragma unroll
    for (int nf = 0; nf < 4; nf++)
#pragma unroll
        for (int r = 0; r < 4; r++) {
            int q = q0 + g * 4 + r;
            out[((size_t)bt * SEQ + q) * 64 + nf * 16 + c] = o[nf][r] / ll[r];
        }
}

// ---------------------------------------------------------------------------
extern "C" void kernel_launch(void* const* d_in, const int* in_sizes, int n_in,
                              void* d_out, int out_size, void* d_ws, size_t ws_size,
                              hipStream_t stream) {
    const float* x  = (const float*)d_in[0];
    const float* Wq = (const float*)d_in[1];
    const float* Wk = (const float*)d_in[2];
    const float* Wv = (const float*)d_in[3];
    float* out = (float*)d_out;

    char* ws = (char*)d_ws;
    short* Wb = (short*)ws;                                   // 192*1024*2   = 384 KB
    short* Qs = (short*)(ws + 393216);                        // 16384*64*2   = 2 MB
    short* Ks = (short*)(ws + 393216 + 2097152);              // 2 MB
    short* Vt = (short*)(ws + 393216 + 2 * 2097152);          // 2 MB  [B][64][S]

    k_convw<<<dim3(192), dim3(256), 0, stream>>>(Wq, Wk, Wv, Wb);
    k_proj <<<dim3(256), dim3(256), 0, stream>>>(x, Wb, Qs, Ks, Vt);
    k_attn <<<dim3(512), dim3(128), 0, stream>>>(Qs, Ks, Vt, out);
}

// Round 3
// 149.131 us; speedup vs baseline: 1.4798x; 1.4798x over previous
//
#include <hip/hip_runtime.h>
#include <hip/hip_bf16.h>

// Problem: y = softmax_causal((x Wq^T)(x Wk^T)^T / 8) (x Wv^T)
// B=4, S=4096, D_EMBED=1024, D=64. Inputs fp32; compute in bf16 MFMA.

typedef short s16x8 __attribute__((ext_vector_type(8)));
typedef float f32x4 __attribute__((ext_vector_type(4)));

#define MFMA16(a, b, c) __builtin_amdgcn_mfma_f32_16x16x32_bf16(a, b, c, 0, 0, 0)

constexpr int SEQ = 4096;
constexpr int DE  = 1024;

// fp32 -> bf16 round-to-nearest-even
__device__ __forceinline__ short f2bf(float f) {
    union { float f; unsigned u; } v; v.f = f;
    unsigned r = (v.u + 0x7FFFu + ((v.u >> 16) & 1u)) >> 16;
    return (short)r;
}

// ---------------------------------------------------------------------------
// Kernel 0: convert W (fp32 [64][1024] x3) to concatenated bf16 [192][1024].
// Q-scale 0.125*log2(e) folded into Wq rows so attention can use exp2 directly.
__global__ __launch_bounds__(256) void k_convw(const float* __restrict__ Wq,
                                               const float* __restrict__ Wk,
                                               const float* __restrict__ Wv,
                                               short* __restrict__ Wb) {
    int i = (blockIdx.x * 256 + threadIdx.x) * 4;
    if (i >= 192 * 1024) return;
    int n = i >> 10, k = i & 1023;
    const float* src; float sc;
    if (n < 64)       { src = Wq + n * 1024;         sc = 0.18033688011112042f; }
    else if (n < 128) { src = Wk + (n - 64) * 1024;  sc = 1.0f; }
    else              { src = Wv + (n - 128) * 1024; sc = 1.0f; }
    float4 v = *(const float4*)(src + k);
    short4 o;
    o.x = f2bf(v.x * sc); o.y = f2bf(v.y * sc);
    o.z = f2bf(v.z * sc); o.w = f2bf(v.w * sc);
    *(short4*)(Wb + i) = o;
}

// ---------------------------------------------------------------------------
// Kernel 1: QKV projection, N-split x3 for occupancy.
// Wave = 16 rows x 64 cols (one of Q/K/V). 3072 waves = 12/CU.
// wid = bid*4+wv; rg = wid/3 (row-group), third = wid%3 (0=Q,1=K,2=V).
__global__ __launch_bounds__(256) void k_proj(const float* __restrict__ x,
                                              const short* __restrict__ Wb,
                                              short* __restrict__ Qs,
                                              short* __restrict__ Ks,
                                              short* __restrict__ Vt) {
    int lane = threadIdx.x & 63, wv = threadIdx.x >> 6;
    int c = lane & 15, g = lane >> 4;
    int wid = blockIdx.x * 4 + wv;       // 0..3071
    int rg = wid / 3;
    int third = wid - rg * 3;
    int m0 = rg * 16;

    const float* xr = x + (size_t)(m0 + c) * DE;          // A rows = l&15
    const short* wbase = Wb + (size_t)third * 64 * DE + (size_t)c * DE;

    f32x4 acc[4];
    const f32x4 z4 = {0.f, 0.f, 0.f, 0.f};
#pragma unroll
    for (int i = 0; i < 4; i++) acc[i] = z4;

#pragma unroll 4
    for (int k0 = 0; k0 < DE; k0 += 32) {
        float4 a0 = *(const float4*)(xr + k0 + g * 8);
        float4 a1 = *(const float4*)(xr + k0 + g * 8 + 4);
        s16x8 a;
        a[0] = f2bf(a0.x); a[1] = f2bf(a0.y); a[2] = f2bf(a0.z); a[3] = f2bf(a0.w);
        a[4] = f2bf(a1.x); a[5] = f2bf(a1.y); a[6] = f2bf(a1.z); a[7] = f2bf(a1.w);
        const short* wp = wbase + k0 + g * 8;
#pragma unroll
        for (int nf = 0; nf < 4; nf++) {
            s16x8 bfr = *(const s16x8*)(wp + (size_t)nf * 16 * DE);
            acc[nf] = MFMA16(a, bfr, acc[nf]);
        }
    }

    // Epilogue. C/D: col = nf*16 + (l&15), row = m0 + (l>>4)*4 + r.
    if (third == 0) {
#pragma unroll
        for (int nf = 0; nf < 4; nf++) {
            int n = nf * 16 + c;
#pragma unroll
            for (int r = 0; r < 4; r++)
                Qs[(size_t)(m0 + g * 4 + r) * 64 + n] = f2bf(acc[nf][r]);
        }
    } else if (third == 1) {
#pragma unroll
        for (int nf = 0; nf < 4; nf++) {
            int n = nf * 16 + c;
#pragma unroll
            for (int r = 0; r < 4; r++)
                Ks[(size_t)(m0 + g * 4 + r) * 64 + n] = f2bf(acc[nf][r]);
        }
    } else {
#pragma unroll
        for (int nf = 0; nf < 4; nf++) {
            int d  = nf * 16 + c;
            int m  = m0 + g * 4;          // 4 consecutive rows -> contiguous s
            int bt = m >> 12;
            int s0 = m & (SEQ - 1);
            short4 o;
            o.x = f2bf(acc[nf][0]); o.y = f2bf(acc[nf][1]);
            o.z = f2bf(acc[nf][2]); o.w = f2bf(acc[nf][3]);
            *(short4*)(Vt + ((size_t)(bt * 64 + d)) * SEQ + s0) = o;
        }
    }
}

// ---------------------------------------------------------------------------
// Kernel 2: causal flash attention, split-K across 4 waves per 16-row q-tile.
// Block = 256 thr (4 waves). Wave w processes k0 = w*64, w*64+256, ...
// Partials (O,m,l) merged via LDS flash-combine. Grid = 1024 (LPT desc j).
__global__ __launch_bounds__(256) void k_attn(const short* __restrict__ Qs,
                                              const short* __restrict__ Ks,
                                              const short* __restrict__ Vt,
                                              float* __restrict__ out) {
    // Union: plds [4][16][72] shorts (9216 B) used in-loop;
    // cO [4][16][68] floats (17408 B) + cM/cL [4][16] after a barrier.
    __shared__ __align__(16) char smem[17920];
    short (*plds)[16][72] = (short (*)[16][72])smem;
    float (*cO)[16][68]   = (float (*)[16][68])smem;
    float* cM = (float*)(smem + 17408);
    float* cL = cM + 64;

    int lane = threadIdx.x & 63, wv = threadIdx.x >> 6;
    int c = lane & 15, g = lane >> 4;
    int bid = blockIdx.x;
    int j  = 255 - (bid >> 2);            // LPT: largest-work blocks first
    int bt = bid & 3;
    int q0 = j * 16;

    const short* Qb = Qs + (size_t)bt * SEQ * 64;
    const short* Kb = Ks + (size_t)bt * SEQ * 64;
    const short* Vb = Vt + (size_t)bt * 64 * SEQ;

    s16x8 qf0 = *(const s16x8*)(Qb + (size_t)(q0 + c) * 64 + g * 8);
    s16x8 qf1 = *(const s16x8*)(Qb + (size_t)(q0 + c) * 64 + 32 + g * 8);

    const f32x4 z4 = {0.f, 0.f, 0.f, 0.f};
    f32x4 o[4];
#pragma unroll
    for (int nf = 0; nf < 4; nf++) o[nf] = z4;
    float m[4], ll[4];
#pragma unroll
    for (int r = 0; r < 4; r++) { m[r] = -1e30f; ll[r] = 0.f; }

    const int kend = q0 + 16;             // causal: k <= q_max = q0+15
    for (int k0 = wv * 64; k0 < kend; k0 += 256) {
        // ---- S = Q K^T ----
        f32x4 sf[4];
#pragma unroll
        for (int kf = 0; kf < 4; kf++) {
            const short* kp = Kb + (size_t)(k0 + kf * 16 + c) * 64 + g * 8;
            s16x8 kb0 = *(const s16x8*)kp;
            s16x8 kb1 = *(const s16x8*)(kp + 32);
            f32x4 t = MFMA16(qf0, kb0, z4);
            sf[kf] = MFMA16(qf1, kb1, t);
        }
        // ---- causal mask ----
        if (k0 + 63 > q0) {
#pragma unroll
            for (int kf = 0; kf < 4; kf++) {
                int k = k0 + kf * 16 + c;
#pragma unroll
                for (int r = 0; r < 4; r++) {
                    int q = q0 + g * 4 + r;
                    if (k > q) sf[kf][r] = -3.0e38f;
                }
            }
        }
        // ---- online softmax (base-2) ----
        float mx[4];
#pragma unroll
        for (int r = 0; r < 4; r++)
            mx[r] = fmaxf(fmaxf(sf[0][r], sf[1][r]), fmaxf(sf[2][r], sf[3][r]));
#pragma unroll
        for (int off = 1; off < 16; off <<= 1) {
#pragma unroll
            for (int r = 0; r < 4; r++)
                mx[r] = fmaxf(mx[r], __shfl_xor(mx[r], off));
        }
        float sc[4];
#pragma unroll
        for (int r = 0; r < 4; r++) {
            float mn = fmaxf(m[r], mx[r]);
            sc[r] = __builtin_amdgcn_exp2f(m[r] - mn);
            m[r] = mn;
        }
#pragma unroll
        for (int kf = 0; kf < 4; kf++)
#pragma unroll
            for (int r = 0; r < 4; r++)
                sf[kf][r] = __builtin_amdgcn_exp2f(sf[kf][r] - m[r]);
        float sum[4];
#pragma unroll
        for (int r = 0; r < 4; r++)
            sum[r] = (sf[0][r] + sf[1][r]) + (sf[2][r] + sf[3][r]);
#pragma unroll
        for (int off = 1; off < 16; off <<= 1) {
#pragma unroll
            for (int r = 0; r < 4; r++)
                sum[r] += __shfl_xor(sum[r], off);
        }
#pragma unroll
        for (int r = 0; r < 4; r++) ll[r] = ll[r] * sc[r] + sum[r];
#pragma unroll
        for (int nf = 0; nf < 4; nf++)
#pragma unroll
            for (int r = 0; r < 4; r++) o[nf][r] *= sc[r];

        // ---- P -> bf16 via per-wave LDS round-trip ----
        asm volatile("s_waitcnt lgkmcnt(0)" ::: "memory");
        __builtin_amdgcn_sched_barrier(0);
#pragma unroll
        for (int kf = 0; kf < 4; kf++)
#pragma unroll
            for (int r = 0; r < 4; r++)
                plds[wv][g * 4 + r][kf * 16 + c] = f2bf(sf[kf][r]);
        asm volatile("s_waitcnt lgkmcnt(0)" ::: "memory");
        __builtin_amdgcn_sched_barrier(0);
        s16x8 pa0 = *(const s16x8*)&plds[wv][c][g * 8];
        s16x8 pa1 = *(const s16x8*)&plds[wv][c][32 + g * 8];

        // ---- O += P V ----
#pragma unroll
        for (int nf = 0; nf < 4; nf++) {
            const short* vp = Vb + (size_t)(nf * 16 + c) * SEQ + k0 + g * 8;
            s16x8 v0 = *(const s16x8*)vp;
            s16x8 v1 = *(const s16x8*)(vp + 32);
            o[nf] = MFMA16(pa0, v0, o[nf]);
            o[nf] = MFMA16(pa1, v1, o[nf]);
        }
    }

    // ---- flash-combine across 4 waves ----
    __syncthreads();                       // all waves done with plds (union!)
#pragma unroll
    for (int nf = 0; nf < 4; nf++)
#pragma unroll
        for (int r = 0; r < 4; r++)
            cO[wv][g * 4 + r][nf * 16 + c] = o[nf][r];
    if (c == 0) {
#pragma unroll
        for (int r = 0; r < 4; r++) {
            cM[wv * 16 + g * 4 + r] = m[r];
            cL[wv * 16 + g * 4 + r] = ll[r];
        }
    }
    __syncthreads();

    // wave w finalizes cols w*16+c, rows g*4+r
#pragma unroll
    for (int r = 0; r < 4; r++) {
        int row = g * 4 + r;
        float m0v = cM[row], m1v = cM[16 + row], m2v = cM[32 + row], m3v = cM[48 + row];
        float Mx = fmaxf(fmaxf(m0v, m1v), fmaxf(m2v, m3v));
        float s0 = __builtin_amdgcn_exp2f(m0v - Mx);
        float s1 = __builtin_amdgcn_exp2f(m1v - Mx);
        float s2 = __builtin_amdgcn_exp2f(m2v - Mx);
        float s3 = __builtin_amdgcn_exp2f(m3v - Mx);
        int col = wv * 16 + c;
        float Ov = s0 * cO[0][row][col] + s1 * cO[1][row][col]
                 + s2 * cO[2][row][col] + s3 * cO[3][row][col];
        float Lv = s0 * cL[row] + s1 * cL[16 + row]
                 + s2 * cL[32 + row] + s3 * cL[48 + row];
        out[((size_t)bt * SEQ + q0 + row) * 64 + col] = Ov / Lv;
    }
}

// ---------------------------------------------------------------------------
extern "C" void kernel_launch(void* const* d_in, const int* in_sizes, int n_in,
                              void* d_out, int out_size, void* d_ws, size_t ws_size,
                              hipStream_t stream) {
    const float* x  = (const float*)d_in[0];
    const float* Wq = (const float*)d_in[1];
    const float* Wk = (const float*)d_in[2];
    const float* Wv = (const float*)d_in[3];
    float* out = (float*)d_out;

    char* ws = (char*)d_ws;
    short* Wb = (short*)ws;                                   // 384 KB
    short* Qs = (short*)(ws + 393216);                        // 2 MB
    short* Ks = (short*)(ws + 393216 + 2097152);              // 2 MB
    short* Vt = (short*)(ws + 393216 + 2 * 2097152);          // 2 MB  [B][64][S]

    k_convw<<<dim3(192), dim3(256), 0, stream>>>(Wq, Wk, Wv, Wb);
    k_proj <<<dim3(768), dim3(256), 0, stream>>>(x, Wb, Qs, Ks, Vt);
    k_attn <<<dim3(1024), dim3(256), 0, stream>>>(Qs, Ks, Vt, out);
}

// Round 4
// 105.702 us; speedup vs baseline: 2.0877x; 1.4109x over previous
//
#include <hip/hip_runtime.h>
#include <hip/hip_bf16.h>

// y = softmax_causal((x Wq^T)(x Wk^T)^T / 8) (x Wv^T)
// B=4, S=4096, D_EMBED=1024, D=64. fp32 in/out; bf16 MFMA compute.

typedef short s16x8 __attribute__((ext_vector_type(8)));
typedef float f32x4 __attribute__((ext_vector_type(4)));
typedef float f32x16 __attribute__((ext_vector_type(16)));
typedef unsigned u32x2 __attribute__((ext_vector_type(2)));

#define MFMA16(a, b, c) __builtin_amdgcn_mfma_f32_16x16x32_bf16(a, b, c, 0, 0, 0)
#define MFMA32(a, b, c) __builtin_amdgcn_mfma_f32_32x32x16_bf16(a, b, c, 0, 0, 0)

constexpr int SEQ = 4096;
constexpr int DE  = 1024;

__device__ __forceinline__ short f2bf(float f) {            // RNE fp32->bf16
    union { float f; unsigned u; } v; v.f = f;
    unsigned r = (v.u + 0x7FFFu + ((v.u >> 16) & 1u)) >> 16;
    return (short)r;
}
__device__ __forceinline__ unsigned fbits(float f) { union { float f; unsigned u; } v; v.f = f; return v.u; }
__device__ __forceinline__ float bitsf(unsigned u) { union { unsigned u; float f; } v; v.u = u; return v.f; }
// pack two fp32 -> (bf16_hi<<16 | bf16_lo), truncation (P in [0,1], err ~2^-9 rel)
__device__ __forceinline__ unsigned pk2(float a, float b) {
    return (fbits(b) & 0xFFFF0000u) | (fbits(a) >> 16);
}

// ---------------------------------------------------------------------------
// Kernel 0: W (fp32 [64][1024] x3) -> bf16 [192][1024]; 0.125*log2e folded in Wq.
__global__ __launch_bounds__(256) void k_convw(const float* __restrict__ Wq,
                                               const float* __restrict__ Wk,
                                               const float* __restrict__ Wv,
                                               short* __restrict__ Wb) {
    int i = (blockIdx.x * 256 + threadIdx.x) * 4;
    if (i >= 192 * 1024) return;
    int n = i >> 10, k = i & 1023;
    const float* src; float sc;
    if (n < 64)       { src = Wq + n * 1024;         sc = 0.18033688011112042f; }
    else if (n < 128) { src = Wk + (n - 64) * 1024;  sc = 1.0f; }
    else              { src = Wv + (n - 128) * 1024; sc = 1.0f; }
    float4 v = *(const float4*)(src + k);
    short4 o;
    o.x = f2bf(v.x * sc); o.y = f2bf(v.y * sc);
    o.z = f2bf(v.z * sc); o.w = f2bf(v.w * sc);
    *(short4*)(Wb + i) = o;
}

// ---------------------------------------------------------------------------
// Kernel 1: QKV projection. Block = 16 rows, 4 waves col-split (48 cols each).
// x tile staged once via global_load_lds (16B, XOR-swizzled), double-buffered.
// 1024 blocks x 256 thr = 16 waves/CU. x read exactly once from HBM.
#define GLDS(gp, lp)                                                          \
    __builtin_amdgcn_global_load_lds(                                         \
        (const __attribute__((address_space(1))) unsigned int*)(gp),          \
        (__attribute__((address_space(3))) unsigned int*)(lp), 16, 0, 0)

__global__ __launch_bounds__(256) void k_proj(const float* __restrict__ x,
                                              const short* __restrict__ Wb,
                                              short* __restrict__ Qs,
                                              short* __restrict__ Ks,
                                              short* __restrict__ Vt) {
    __shared__ __align__(16) float xb[2][16][64];    // 2 x 4KB, XOR-swizzled rows
    int tid = threadIdx.x;
    int lane = tid & 63, wv = tid >> 6;
    int c = lane & 15, g = lane >> 4;
    int m0 = blockIdx.x * 16;

    // staging map: thread t holds LDS bytes [t*16, t*16+16) = row (t>>4),
    // col-bytes ((t&15)*16) ; content pre-swizzled: global col ^= (row&7)<<4
    int sr = tid >> 4, sc4 = tid & 15;
    const char* gsrc = (const char*)x + ((size_t)(m0 + sr) << 12)
                     + (size_t)(((sc4 << 4) ^ ((sr & 7) << 4)));

    f32x4 acc[3];
#pragma unroll
    for (int f = 0; f < 3; f++) acc[f] = (f32x4){0.f, 0.f, 0.f, 0.f};

    int n0 = wv * 48;
    const short* wb0 = Wb + (size_t)(n0 + c) * DE;

    GLDS(gsrc, (char*)&xb[0][0][0] + tid * 16);

    for (int kk = 0; kk < 16; kk++) {
        int cur = kk & 1;
        asm volatile("s_waitcnt vmcnt(0)" ::: "memory");
        __syncthreads();
        if (kk < 15)
            GLDS(gsrc + ((kk + 1) << 8), (char*)&xb[cur ^ 1][0][0] + tid * 16);

        const char* rowp = (const char*)&xb[cur][c][0];
        int swz = (c & 7) << 4;
#pragma unroll
        for (int kc = 0; kc < 2; kc++) {
            int base = kc * 128 + g * 32;
            float4 a0 = *(const float4*)(rowp + ((base) ^ swz));
            float4 a1 = *(const float4*)(rowp + ((base + 16) ^ swz));
            s16x8 a;
            a[0] = f2bf(a0.x); a[1] = f2bf(a0.y); a[2] = f2bf(a0.z); a[3] = f2bf(a0.w);
            a[4] = f2bf(a1.x); a[5] = f2bf(a1.y); a[6] = f2bf(a1.z); a[7] = f2bf(a1.w);
            const short* wp = wb0 + kk * 64 + kc * 32 + g * 8;
#pragma unroll
            for (int f = 0; f < 3; f++) {
                s16x8 bfr = *(const s16x8*)(wp + (size_t)f * 16 * DE);
                acc[f] = MFMA16(a, bfr, acc[f]);
            }
        }
    }

    // Epilogue: C/D col = n0+f*16+(l&15), row = m0 + g*4 + r. 16-col tiles
    // never straddle the Q/K/V boundaries (all multiples of 16).
#pragma unroll
    for (int f = 0; f < 3; f++) {
        int n = n0 + f * 16;
        if (n < 64) {
            int col = n + c;
#pragma unroll
            for (int r = 0; r < 4; r++)
                Qs[(size_t)(m0 + g * 4 + r) * 64 + col] = f2bf(acc[f][r]);
        } else if (n < 128) {
            int col = n - 64 + c;
#pragma unroll
            for (int r = 0; r < 4; r++)
                Ks[(size_t)(m0 + g * 4 + r) * 64 + col] = f2bf(acc[f][r]);
        } else {
            int d  = n - 128 + c;
            int mm = m0 + g * 4;
            int bt = mm >> 12, s0 = mm & (SEQ - 1);
            short4 o;
            o.x = f2bf(acc[f][0]); o.y = f2bf(acc[f][1]);
            o.z = f2bf(acc[f][2]); o.w = f2bf(acc[f][3]);
            *(short4*)(Vt + ((size_t)(bt * 64 + d)) * SEQ + s0) = o;
        }
    }
}

// ---------------------------------------------------------------------------
// Kernel 2: causal flash attention, swapped-QK 32x32x16 (lane = q for P/m/l/O^T).
// Block = 4 waves split-K over one 32-row q-tile; flash-combine via LDS.
// S^T = mfma(A=K, B=Q); O^T = mfma(A=V^T, B=P^T). No in-loop LDS/barriers.
__global__ __launch_bounds__(256) void k_attn(const short* __restrict__ Qs,
                                              const short* __restrict__ Ks,
                                              const short* __restrict__ Vt,
                                              float* __restrict__ out) {
    __shared__ __align__(16) float pO[4][64][33];   // [wave][dv][q], 2-way free
    __shared__ float pM[4][32];
    __shared__ float pL[4][32];

    int tid = threadIdx.x;
    int l = tid & 63, wv = tid >> 6;
    int q = l & 31, hi = l >> 5;
    int bid = blockIdx.x;
    int j = 127 - (bid >> 2), bt = bid & 3;   // LPT: heavy tiles first
    int q0 = j * 32;

    const short* Qb = Qs + (size_t)bt * SEQ * 64;
    const short* Kb = Ks + (size_t)bt * SEQ * 64;
    const short* Vb = Vt + (size_t)bt * 64 * SEQ;

    // Q as QK^T B-operand: lane(q,hi) holds Q[q0+q][dch*16 + hi*8 + i]
    s16x8 qf[4];
#pragma unroll
    for (int d = 0; d < 4; d++)
        qf[d] = *(const s16x8*)(Qb + (size_t)(q0 + q) * 64 + d * 16 + hi * 8);

    f32x16 o0 = {}, o1 = {};        // O^T tiles dv[0:32),[32:64): col=q, row=dv
    float m = -1e30f, ll = 0.f;

    for (int k0 = wv * 32; k0 < q0 + 32; k0 += 128) {
        // ---- S^T = K Q^T : A-row = k0+(l&31), D: col=q, row=k_local ----
        const short* kp = Kb + (size_t)(k0 + q) * 64 + hi * 8;
        f32x16 s = {};
        s = MFMA32(*(const s16x8*)(kp),      qf[0], s);
        s = MFMA32(*(const s16x8*)(kp + 16), qf[1], s);
        s = MFMA32(*(const s16x8*)(kp + 32), qf[2], s);
        s = MFMA32(*(const s16x8*)(kp + 48), qf[3], s);

        if (k0 + 31 > q0) {                  // causal mask near diagonal
#pragma unroll
            for (int r = 0; r < 16; r++) {
                int kk = k0 + (r & 3) + 8 * (r >> 2) + 4 * hi;
                if (kk > q0 + q) s[r] = -3.0e38f;
            }
        }

        // ---- in-register softmax (base-2; scale folded in Wq) ----
        float t0 = fmaxf(fmaxf(fmaxf(s[0], s[1]), fmaxf(s[2], s[3])),
                         fmaxf(fmaxf(s[4], s[5]), fmaxf(s[6], s[7])));
        float t1 = fmaxf(fmaxf(fmaxf(s[8], s[9]), fmaxf(s[10], s[11])),
                         fmaxf(fmaxf(s[12], s[13]), fmaxf(s[14], s[15])));
        float tm = fmaxf(t0, t1);
        u32x2 sw = __builtin_amdgcn_permlane32_swap(fbits(tm), fbits(tm), false, false);
        tm = fmaxf(bitsf(sw[0]), bitsf(sw[1]));      // combine lane ^ lane+32
        float mn = fmaxf(m, tm);
        float scale = __builtin_amdgcn_exp2f(m - mn);
        m = mn;
#pragma unroll
        for (int r = 0; r < 16; r++) s[r] = __builtin_amdgcn_exp2f(s[r] - mn);
        float u0s = ((s[0] + s[1]) + (s[2] + s[3])) + ((s[4] + s[5]) + (s[6] + s[7]));
        float u1s = ((s[8] + s[9]) + (s[10] + s[11])) + ((s[12] + s[13]) + (s[14] + s[15]));
        float ts = u0s + u1s;
        sw = __builtin_amdgcn_permlane32_swap(fbits(ts), fbits(ts), false, false);
        ts = bitsf(sw[0]) + bitsf(sw[1]);
        ll = ll * scale + ts;
        o0 *= scale; o1 *= scale;

        // ---- P -> bf16 B-frags via pack + permlane32_swap (no LDS) ----
        unsigned A0 = pk2(s[0], s[1]),  B0 = pk2(s[2], s[3]);
        unsigned A1 = pk2(s[4], s[5]),  B1 = pk2(s[6], s[7]);
        unsigned A2 = pk2(s[8], s[9]),  B2 = pk2(s[10], s[11]);
        unsigned A3 = pk2(s[12], s[13]), B3 = pk2(s[14], s[15]);
        u32x2 r0 = __builtin_amdgcn_permlane32_swap(A0, A1, false, false);
        u32x2 r1 = __builtin_amdgcn_permlane32_swap(B0, B1, false, false);
        u32x2 r2 = __builtin_amdgcn_permlane32_swap(A2, A3, false, false);
        u32x2 r3 = __builtin_amdgcn_permlane32_swap(B2, B3, false, false);
        union { unsigned u[4]; s16x8 v; } p0u, p1u;
        p0u.u[0] = r0[0]; p0u.u[1] = r1[0]; p0u.u[2] = r0[1]; p0u.u[3] = r1[1];
        p1u.u[0] = r2[0]; p1u.u[1] = r3[0]; p1u.u[2] = r2[1]; p1u.u[3] = r3[1];

        // ---- O^T += V^T P^T : A-row = dv (Vt s-contiguous), B = P frags ----
        const short* vp = Vb + (size_t)q * SEQ + k0 + hi * 8;
        o0 = MFMA32(*(const s16x8*)(vp),                 p0u.v, o0);
        o0 = MFMA32(*(const s16x8*)(vp + 16),            p1u.v, o0);
        o1 = MFMA32(*(const s16x8*)(vp + 32 * SEQ),      p0u.v, o1);
        o1 = MFMA32(*(const s16x8*)(vp + 32 * SEQ + 16), p1u.v, o1);
    }

    // ---- flash-combine across the 4 split-K waves ----
    __syncthreads();
#pragma unroll
    for (int r = 0; r < 16; r++) {
        int dv = (r & 3) + 8 * (r >> 2) + 4 * hi;
        pO[wv][dv][q]      = o0[r];
        pO[wv][dv + 32][q] = o1[r];
    }
    if (hi == 0) { pM[wv][q] = m; pL[wv][q] = ll; }
    __syncthreads();

    int q2 = tid >> 3, d0 = (tid & 7) * 8;    // thread -> (q, 8 dv)
    float m0v = pM[0][q2], m1v = pM[1][q2], m2v = pM[2][q2], m3v = pM[3][q2];
    float M = fmaxf(fmaxf(m0v, m1v), fmaxf(m2v, m3v));
    float w0 = __builtin_amdgcn_exp2f(m0v - M);
    float w1 = __builtin_amdgcn_exp2f(m1v - M);
    float w2 = __builtin_amdgcn_exp2f(m2v - M);
    float w3 = __builtin_amdgcn_exp2f(m3v - M);
    float L = w0 * pL[0][q2] + w1 * pL[1][q2] + w2 * pL[2][q2] + w3 * pL[3][q2];
    float inv = 1.0f / L;
    float res[8];
#pragma unroll
    for (int i = 0; i < 8; i++)
        res[i] = (w0 * pO[0][d0 + i][q2] + w1 * pO[1][d0 + i][q2]
                + w2 * pO[2][d0 + i][q2] + w3 * pO[3][d0 + i][q2]) * inv;
    float* op = out + ((size_t)bt * SEQ + q0 + q2) * 64 + d0;
    float4 f0 = {res[0], res[1], res[2], res[3]};
    float4 f1 = {res[4], res[5], res[6], res[7]};
    *(float4*)op = f0;
    *(float4*)(op + 4) = f1;
}

// ---------------------------------------------------------------------------
extern "C" void kernel_launch(void* const* d_in, const int* in_sizes, int n_in,
                              void* d_out, int out_size, void* d_ws, size_t ws_size,
                              hipStream_t stream) {
    const float* x  = (const float*)d_in[0];
    const float* Wq = (const float*)d_in[1];
    const float* Wk = (const float*)d_in[2];
    const float* Wv = (const float*)d_in[3];
    float* out = (float*)d_out;

    char* ws = (char*)d_ws;
    short* Wb = (short*)ws;                                   // 384 KB
    short* Qs = (short*)(ws + 393216);                        // 2 MB
    short* Ks = (short*)(ws + 393216 + 2097152);              // 2 MB
    short* Vt = (short*)(ws + 393216 + 2 * 2097152);          // 2 MB  [B][64][S]

    k_convw<<<dim3(192),  dim3(256), 0, stream>>>(Wq, Wk, Wv, Wb);
    k_proj <<<dim3(1024), dim3(256), 0, stream>>>(x, Wb, Qs, Ks, Vt);
    k_attn <<<dim3(512),  dim3(256), 0, stream>>>(Qs, Ks, Vt, out);
}

// Round 5
// 80.116 us; speedup vs baseline: 2.7545x; 1.3194x over previous
//
#include <hip/hip_runtime.h>
#include <hip/hip_bf16.h>

// y = softmax_causal((x Wq^T)(x Wk^T)^T / 8) (x Wv^T)
// B=4, S=4096, D_EMBED=1024, D=64. fp32 in/out; bf16 MFMA compute.

typedef short s16x8 __attribute__((ext_vector_type(8)));
typedef float f32x4 __attribute__((ext_vector_type(4)));
typedef float f32x16 __attribute__((ext_vector_type(16)));
typedef unsigned u32x2 __attribute__((ext_vector_type(2)));

#define MFMA16(a, b, c) __builtin_amdgcn_mfma_f32_16x16x32_bf16(a, b, c, 0, 0, 0)
#define MFMA32(a, b, c) __builtin_amdgcn_mfma_f32_32x32x16_bf16(a, b, c, 0, 0, 0)

constexpr int SEQ = 4096;
constexpr int DE  = 1024;

__device__ __forceinline__ short f2bf(float f) {            // RNE fp32->bf16
    union { float f; unsigned u; } v; v.f = f;
    unsigned r = (v.u + 0x7FFFu + ((v.u >> 16) & 1u)) >> 16;
    return (short)r;
}
__device__ __forceinline__ unsigned fbits(float f) { union { float f; unsigned u; } v; v.f = f; return v.u; }
__device__ __forceinline__ float bitsf(unsigned u) { union { unsigned u; float f; } v; v.u = u; return v.f; }
__device__ __forceinline__ unsigned pk2(float a, float b) {  // 2xf32 -> packed bf16 (trunc)
    return (fbits(b) & 0xFFFF0000u) | (fbits(a) >> 16);
}

#define GLDS(gp, lp)                                                          \
    __builtin_amdgcn_global_load_lds(                                         \
        (const __attribute__((address_space(1))) unsigned int*)(gp),          \
        (__attribute__((address_space(3))) unsigned int*)(lp), 16, 0, 0)

// ---------------------------------------------------------------------------
// Kernel 0: W (fp32 [64][1024] x3) -> bf16 [192][1024]; 0.125*log2e folded in Wq.
__global__ __launch_bounds__(256) void k_convw(const float* __restrict__ Wq,
                                               const float* __restrict__ Wk,
                                               const float* __restrict__ Wv,
                                               short* __restrict__ Wb) {
    int i = (blockIdx.x * 256 + threadIdx.x) * 4;
    if (i >= 192 * 1024) return;
    int n = i >> 10, k = i & 1023;
    const float* src; float sc;
    if (n < 64)       { src = Wq + n * 1024;         sc = 0.18033688011112042f; }
    else if (n < 128) { src = Wk + (n - 64) * 1024;  sc = 1.0f; }
    else              { src = Wv + (n - 128) * 1024; sc = 1.0f; }
    float4 v = *(const float4*)(src + k);
    short4 o;
    o.x = f2bf(v.x * sc); o.y = f2bf(v.y * sc);
    o.z = f2bf(v.z * sc); o.w = f2bf(v.w * sc);
    *(short4*)(Wb + i) = o;
}

// ---------------------------------------------------------------------------
// Kernel 1: QKV projection as counted-vmcnt pipelined GEMM.
// BM=64, BN=192 (all N), BK=64, 16 K-steps. 8 waves: wave = (rg = wv&3)*16 rows
// x (nh = wv>>2)*96 cols (6 MFMA16 frags). Both x-tile (16KB f32) and W-tile
// (24KB bf16) staged via global_load_lds: exactly 5 GLDS/thread/step ->
// vmcnt(5) = prev step complete, 1 step always in flight. Raw s_barrier only.
// XOR-swizzle ((row&7)<<4) applied on SOURCE at stage and on LDS reads (#21).
__global__ __launch_bounds__(512) void k_proj(const float* __restrict__ x,
                                              const short* __restrict__ Wb,
                                              short* __restrict__ Qs,
                                              short* __restrict__ Ks,
                                              short* __restrict__ Vt) {
    __shared__ __align__(16) char lds[2][40960];   // per buf: A 16KB | W 24KB
    const int tid  = threadIdx.x;
    const int lane = tid & 63;
    const int c = lane & 15, g = (lane >> 4) & 3;
    const int wv = tid >> 6;
    const int rg = wv & 3, nh = wv >> 2;
    const int n0 = nh * 96;
    const int m0 = blockIdx.x * 64;

    // --- staging sources (pre-swizzled so linear GLDS dest + swizzled read match)
    const int Ar  = tid >> 4;                                   // A row 0..31 (h adds 32)
    const int Acs = ((tid & 15) << 4) ^ ((Ar & 7) << 4);        // src byte col
    const char* aS0 = (const char*)x + (((size_t)(m0 + Ar)) << 12) + Acs;
    const char* aS1 = aS0 + ((size_t)32 << 12);
    const int Wr  = tid >> 3;                                   // W row 0..63 (p adds 64)
    const int Wcs = ((tid & 7) << 4) ^ ((Wr & 7) << 4);
    const char* wS0 = (const char*)Wb + (((size_t)Wr) << 11) + Wcs;
    const char* wS1 = wS0 + ((size_t)64 << 11);
    const char* wS2 = wS0 + ((size_t)128 << 11);

    char* db0 = &lds[0][0] + tid * 16;     // linear GLDS dests (lane-stride 16)
    char* db1 = &lds[1][0] + tid * 16;

    // --- compute-side bases
    const int arow = rg * 16 + c;
    const int swz  = (c & 7) << 4;
    const char* aR[2] = { &lds[0][0] + arow * 256, &lds[1][0] + arow * 256 };
    const char* wR[2][6];
#pragma unroll
    for (int nf = 0; nf < 6; nf++) {
        int wrow = n0 + nf * 16 + c;
        wR[0][nf] = &lds[0][0] + 16384 + wrow * 128;
        wR[1][nf] = &lds[1][0] + 16384 + wrow * 128;
    }

    f32x4 acc[6];
#pragma unroll
    for (int i = 0; i < 6; i++) acc[i] = (f32x4){0.f, 0.f, 0.f, 0.f};

#define STAGE(kk, db) {                                   \
        GLDS(aS0 + (kk) * 256, (db));                     \
        GLDS(aS1 + (kk) * 256, (db) + 8192);              \
        GLDS(wS0 + (kk) * 128, (db) + 16384);             \
        GLDS(wS1 + (kk) * 128, (db) + 24576);             \
        GLDS(wS2 + (kk) * 128, (db) + 32768); }

#define COMPUTE(bi) {                                                          \
        _Pragma("unroll")                                                      \
        for (int kc = 0; kc < 2; kc++) {                                       \
            float4 a0 = *(const float4*)(aR[bi] + ((kc*128 + g*32)      ^ swz)); \
            float4 a1 = *(const float4*)(aR[bi] + ((kc*128 + g*32 + 16) ^ swz)); \
            s16x8 a;                                                           \
            a[0]=f2bf(a0.x); a[1]=f2bf(a0.y); a[2]=f2bf(a0.z); a[3]=f2bf(a0.w); \
            a[4]=f2bf(a1.x); a[5]=f2bf(a1.y); a[6]=f2bf(a1.z); a[7]=f2bf(a1.w); \
            _Pragma("unroll")                                                  \
            for (int nf = 0; nf < 6; nf++) {                                   \
                s16x8 bfr = *(const s16x8*)(wR[bi][nf] + ((kc*64 + g*16) ^ swz)); \
                acc[nf] = MFMA16(a, bfr, acc[nf]);                             \
            }                                                                  \
        } }

    STAGE(0, db0);
    STAGE(1, db1);

    for (int kk = 0; kk < 15; kk++) {
        asm volatile("s_waitcnt vmcnt(5)" ::: "memory");   // step kk landed
        __builtin_amdgcn_sched_barrier(0);
        __builtin_amdgcn_s_barrier();
        if (kk & 1) COMPUTE(1) else COMPUTE(0)
        asm volatile("s_waitcnt lgkmcnt(0)" ::: "memory"); // my reads retired
        __builtin_amdgcn_sched_barrier(0);
        __builtin_amdgcn_s_barrier();                      // all waves done reading
        if (kk < 14) { if (kk & 1) STAGE(kk + 2, db1) else STAGE(kk + 2, db0) }
    }
    asm volatile("s_waitcnt vmcnt(0)" ::: "memory");       // last step: full drain
    __builtin_amdgcn_sched_barrier(0);
    __builtin_amdgcn_s_barrier();
    COMPUTE(1)                                             // kk=15 -> buf 1
#undef STAGE
#undef COMPUTE

    // Epilogue: C/D col = n0 + nf*16 + c, row = m0 + rg*16 + g*4 + r.
#pragma unroll
    for (int nf = 0; nf < 6; nf++) {
        int col16 = n0 + nf * 16;
        if (col16 < 64) {
            int col = col16 + c;
#pragma unroll
            for (int r = 0; r < 4; r++)
                Qs[(size_t)(m0 + rg * 16 + g * 4 + r) * 64 + col] = f2bf(acc[nf][r]);
        } else if (col16 < 128) {
            int col = col16 - 64 + c;
#pragma unroll
            for (int r = 0; r < 4; r++)
                Ks[(size_t)(m0 + rg * 16 + g * 4 + r) * 64 + col] = f2bf(acc[nf][r]);
        } else {
            int d  = col16 - 128 + c;
            int mm = m0 + rg * 16 + g * 4;
            int bt = mm >> 12, s0 = mm & (SEQ - 1);
            short4 o;
            o.x = f2bf(acc[nf][0]); o.y = f2bf(acc[nf][1]);
            o.z = f2bf(acc[nf][2]); o.w = f2bf(acc[nf][3]);
            *(short4*)(Vt + ((size_t)(bt * 64 + d)) * SEQ + s0) = o;
        }
    }
}

// ---------------------------------------------------------------------------
// Kernel 2: causal flash attention, swapped-QK 32x32x16, split-K x8 waves.
// Block = 512 thr (8 waves) on one 32-row q-tile; wave wv: k0 = wv*32 step 256.
// 16 waves/CU. Flash-combine across 8 partials via LDS. LPT grid order.
__global__ __launch_bounds__(512) void k_attn(const short* __restrict__ Qs,
                                              const short* __restrict__ Ks,
                                              const short* __restrict__ Vt,
                                              float* __restrict__ out) {
    __shared__ __align__(16) float pO[8][64][33];   // 67.6 KB
    __shared__ float pM[8][32];
    __shared__ float pL[8][32];

    int tid = threadIdx.x;
    int l = tid & 63, wv = tid >> 6;
    int q = l & 31, hi = l >> 5;
    int bid = blockIdx.x;
    int j = 127 - (bid >> 2), bt = bid & 3;   // LPT: heavy tiles first
    int q0 = j * 32;

    const short* Qb = Qs + (size_t)bt * SEQ * 64;
    const short* Kb = Ks + (size_t)bt * SEQ * 64;
    const short* Vb = Vt + (size_t)bt * 64 * SEQ;

    s16x8 qf[4];
#pragma unroll
    for (int d = 0; d < 4; d++)
        qf[d] = *(const s16x8*)(Qb + (size_t)(q0 + q) * 64 + d * 16 + hi * 8);

    f32x16 o0 = {}, o1 = {};
    float m = -1e30f, ll = 0.f;

    for (int k0 = wv * 32; k0 < q0 + 32; k0 += 256) {
        // ---- S^T = K Q^T ----
        const short* kp = Kb + (size_t)(k0 + q) * 64 + hi * 8;
        f32x16 s = {};
        s = MFMA32(*(const s16x8*)(kp),      qf[0], s);
        s = MFMA32(*(const s16x8*)(kp + 16), qf[1], s);
        s = MFMA32(*(const s16x8*)(kp + 32), qf[2], s);
        s = MFMA32(*(const s16x8*)(kp + 48), qf[3], s);

        if (k0 + 31 > q0) {
#pragma unroll
            for (int r = 0; r < 16; r++) {
                int kk = k0 + (r & 3) + 8 * (r >> 2) + 4 * hi;
                if (kk > q0 + q) s[r] = -3.0e38f;
            }
        }

        // ---- in-register softmax (base-2) ----
        float t0 = fmaxf(fmaxf(fmaxf(s[0], s[1]), fmaxf(s[2], s[3])),
                         fmaxf(fmaxf(s[4], s[5]), fmaxf(s[6], s[7])));
        float t1 = fmaxf(fmaxf(fmaxf(s[8], s[9]), fmaxf(s[10], s[11])),
                         fmaxf(fmaxf(s[12], s[13]), fmaxf(s[14], s[15])));
        float tm = fmaxf(t0, t1);
        u32x2 sw = __builtin_amdgcn_permlane32_swap(fbits(tm), fbits(tm), false, false);
        tm = fmaxf(bitsf(sw[0]), bitsf(sw[1]));
        float mn = fmaxf(m, tm);
        float scale = __builtin_amdgcn_exp2f(m - mn);
        m = mn;
#pragma unroll
        for (int r = 0; r < 16; r++) s[r] = __builtin_amdgcn_exp2f(s[r] - mn);
        float u0s = ((s[0] + s[1]) + (s[2] + s[3])) + ((s[4] + s[5]) + (s[6] + s[7]));
        float u1s = ((s[8] + s[9]) + (s[10] + s[11])) + ((s[12] + s[13]) + (s[14] + s[15]));
        float ts = u0s + u1s;
        sw = __builtin_amdgcn_permlane32_swap(fbits(ts), fbits(ts), false, false);
        ts = bitsf(sw[0]) + bitsf(sw[1]);
        ll = ll * scale + ts;
        o0 *= scale; o1 *= scale;

        // ---- P -> bf16 B-frags via pack + permlane32_swap ----
        unsigned A0 = pk2(s[0], s[1]),   B0 = pk2(s[2], s[3]);
        unsigned A1 = pk2(s[4], s[5]),   B1 = pk2(s[6], s[7]);
        unsigned A2 = pk2(s[8], s[9]),   B2 = pk2(s[10], s[11]);
        unsigned A3 = pk2(s[12], s[13]), B3 = pk2(s[14], s[15]);
        u32x2 r0 = __builtin_amdgcn_permlane32_swap(A0, A1, false, false);
        u32x2 r1 = __builtin_amdgcn_permlane32_swap(B0, B1, false, false);
        u32x2 r2 = __builtin_amdgcn_permlane32_swap(A2, A3, false, false);
        u32x2 r3 = __builtin_amdgcn_permlane32_swap(B2, B3, false, false);
        union { unsigned u[4]; s16x8 v; } p0u, p1u;
        p0u.u[0] = r0[0]; p0u.u[1] = r1[0]; p0u.u[2] = r0[1]; p0u.u[3] = r1[1];
        p1u.u[0] = r2[0]; p1u.u[1] = r3[0]; p1u.u[2] = r2[1]; p1u.u[3] = r3[1];

        // ---- O^T += V^T P^T ----
        const short* vp = Vb + (size_t)q * SEQ + k0 + hi * 8;
        o0 = MFMA32(*(const s16x8*)(vp),                 p0u.v, o0);
        o0 = MFMA32(*(const s16x8*)(vp + 16),            p1u.v, o0);
        o1 = MFMA32(*(const s16x8*)(vp + 32 * SEQ),      p0u.v, o1);
        o1 = MFMA32(*(const s16x8*)(vp + 32 * SEQ + 16), p1u.v, o1);
    }

    // ---- flash-combine across 8 split-K waves ----
    __syncthreads();
#pragma unroll
    for (int r = 0; r < 16; r++) {
        int dv = (r & 3) + 8 * (r >> 2) + 4 * hi;
        pO[wv][dv][q]      = o0[r];
        pO[wv][dv + 32][q] = o1[r];
    }
    if (hi == 0) { pM[wv][q] = m; pL[wv][q] = ll; }
    __syncthreads();

    int q2 = tid >> 4, d0 = (tid & 15) * 4;   // thread -> (q, 4 dv)
    float mw[8], wwt[8];
    float M = -1e30f;
#pragma unroll
    for (int w = 0; w < 8; w++) { mw[w] = pM[w][q2]; M = fmaxf(M, mw[w]); }
    float L = 0.f;
#pragma unroll
    for (int w = 0; w < 8; w++) { wwt[w] = __builtin_amdgcn_exp2f(mw[w] - M); L += wwt[w] * pL[w][q2]; }
    float inv = 1.0f / L;
    float res[4];
#pragma unroll
    for (int i = 0; i < 4; i++) {
        float acc = 0.f;
#pragma unroll
        for (int w = 0; w < 8; w++) acc += wwt[w] * pO[w][d0 + i][q2];
        res[i] = acc * inv;
    }
    float4 f0 = {res[0], res[1], res[2], res[3]};
    *(float4*)(out + ((size_t)bt * SEQ + q0 + q2) * 64 + d0) = f0;
}

// ---------------------------------------------------------------------------
extern "C" void kernel_launch(void* const* d_in, const int* in_sizes, int n_in,
                              void* d_out, int out_size, void* d_ws, size_t ws_size,
                              hipStream_t stream) {
    const float* x  = (const float*)d_in[0];
    const float* Wq = (const float*)d_in[1];
    const float* Wk = (const float*)d_in[2];
    const float* Wv = (const float*)d_in[3];
    float* out = (float*)d_out;

    char* ws = (char*)d_ws;
    short* Wb = (short*)ws;                                   // 384 KB
    short* Qs = (short*)(ws + 393216);                        // 2 MB
    short* Ks = (short*)(ws + 393216 + 2097152);              // 2 MB
    short* Vt = (short*)(ws + 393216 + 2 * 2097152);          // 2 MB  [B][64][S]

    k_convw<<<dim3(192), dim3(256), 0, stream>>>(Wq, Wk, Wv, Wb);
    k_proj <<<dim3(256), dim3(512), 0, stream>>>(x, Wb, Qs, Ks, Vt);
    k_attn <<<dim3(512), dim3(512), 0, stream>>>(Qs, Ks, Vt, out);
}

// Round 6
// 67.372 us; speedup vs baseline: 3.2755x; 1.1892x over previous
//
#include <hip/hip_runtime.h>
#include <hip/hip_bf16.h>

// y = softmax_causal((x Wq^T)(x Wk^T)^T / 8) (x Wv^T)
// B=4, S=4096, D_EMBED=1024, D=64. fp32 in/out; bf16 MFMA compute.

typedef short s16x8 __attribute__((ext_vector_type(8)));
typedef float f32x4 __attribute__((ext_vector_type(4)));
typedef float f32x16 __attribute__((ext_vector_type(16)));
typedef unsigned u32x2 __attribute__((ext_vector_type(2)));

#define MFMA16(a, b, c) __builtin_amdgcn_mfma_f32_16x16x32_bf16(a, b, c, 0, 0, 0)
#define MFMA32(a, b, c) __builtin_amdgcn_mfma_f32_32x32x16_bf16(a, b, c, 0, 0, 0)

constexpr int SEQ = 4096;
constexpr int DE  = 1024;

__device__ __forceinline__ short f2bf(float f) {            // RNE fp32->bf16
    union { float f; unsigned u; } v; v.f = f;
    unsigned r = (v.u + 0x7FFFu + ((v.u >> 16) & 1u)) >> 16;
    return (short)r;
}
__device__ __forceinline__ unsigned fbits(float f) { union { float f; unsigned u; } v; v.f = f; return v.u; }
__device__ __forceinline__ float bitsf(unsigned u) { union { unsigned u; float f; } v; v.u = u; return v.f; }
__device__ __forceinline__ unsigned pk2(float a, float b) {  // 2xf32 -> packed bf16 (trunc)
    return (fbits(b) & 0xFFFF0000u) | (fbits(a) >> 16);
}

#define GLDS(gp, lp)                                                          \
    __builtin_amdgcn_global_load_lds(                                         \
        (const __attribute__((address_space(1))) unsigned int*)(gp),          \
        (__attribute__((address_space(3))) unsigned int*)(lp), 16, 0, 0)

// ---------------------------------------------------------------------------
// Kernel 0: W (fp32 [64][1024] x3) -> bf16 [192][1024]; 0.125*log2e folded in Wq.
__global__ __launch_bounds__(256) void k_convw(const float* __restrict__ Wq,
                                               const float* __restrict__ Wk,
                                               const float* __restrict__ Wv,
                                               short* __restrict__ Wb) {
    int i = (blockIdx.x * 256 + threadIdx.x) * 4;
    if (i >= 192 * 1024) return;
    int n = i >> 10, k = i & 1023;
    const float* src; float sc;
    if (n < 64)       { src = Wq + n * 1024;         sc = 0.18033688011112042f; }
    else if (n < 128) { src = Wk + (n - 64) * 1024;  sc = 1.0f; }
    else              { src = Wv + (n - 128) * 1024; sc = 1.0f; }
    float4 v = *(const float4*)(src + k);
    short4 o;
    o.x = f2bf(v.x * sc); o.y = f2bf(v.y * sc);
    o.z = f2bf(v.z * sc); o.w = f2bf(v.w * sc);
    *(short4*)(Wb + i) = o;
}

// ---------------------------------------------------------------------------
// Kernel 1: QKV projection as counted-vmcnt pipelined GEMM (unchanged, R5).
__global__ __launch_bounds__(512) void k_proj(const float* __restrict__ x,
                                              const short* __restrict__ Wb,
                                              short* __restrict__ Qs,
                                              short* __restrict__ Ks,
                                              short* __restrict__ Vt) {
    __shared__ __align__(16) char lds[2][40960];   // per buf: A 16KB | W 24KB
    const int tid  = threadIdx.x;
    const int lane = tid & 63;
    const int c = lane & 15, g = (lane >> 4) & 3;
    const int wv = tid >> 6;
    const int rg = wv & 3, nh = wv >> 2;
    const int n0 = nh * 96;
    const int m0 = blockIdx.x * 64;

    const int Ar  = tid >> 4;
    const int Acs = ((tid & 15) << 4) ^ ((Ar & 7) << 4);
    const char* aS0 = (const char*)x + (((size_t)(m0 + Ar)) << 12) + Acs;
    const char* aS1 = aS0 + ((size_t)32 << 12);
    const int Wr  = tid >> 3;
    const int Wcs = ((tid & 7) << 4) ^ ((Wr & 7) << 4);
    const char* wS0 = (const char*)Wb + (((size_t)Wr) << 11) + Wcs;
    const char* wS1 = wS0 + ((size_t)64 << 11);
    const char* wS2 = wS0 + ((size_t)128 << 11);

    char* db0 = &lds[0][0] + tid * 16;
    char* db1 = &lds[1][0] + tid * 16;

    const int arow = rg * 16 + c;
    const int swz  = (c & 7) << 4;
    const char* aR[2] = { &lds[0][0] + arow * 256, &lds[1][0] + arow * 256 };
    const char* wR[2][6];
#pragma unroll
    for (int nf = 0; nf < 6; nf++) {
        int wrow = n0 + nf * 16 + c;
        wR[0][nf] = &lds[0][0] + 16384 + wrow * 128;
        wR[1][nf] = &lds[1][0] + 16384 + wrow * 128;
    }

    f32x4 acc[6];
#pragma unroll
    for (int i = 0; i < 6; i++) acc[i] = (f32x4){0.f, 0.f, 0.f, 0.f};

#define PSTAGE(kk, db) {                                  \
        GLDS(aS0 + (kk) * 256, (db));                     \
        GLDS(aS1 + (kk) * 256, (db) + 8192);              \
        GLDS(wS0 + (kk) * 128, (db) + 16384);             \
        GLDS(wS1 + (kk) * 128, (db) + 24576);             \
        GLDS(wS2 + (kk) * 128, (db) + 32768); }

#define PCOMPUTE(bi) {                                                         \
        _Pragma("unroll")                                                      \
        for (int kc = 0; kc < 2; kc++) {                                       \
            float4 a0 = *(const float4*)(aR[bi] + ((kc*128 + g*32)      ^ swz)); \
            float4 a1 = *(const float4*)(aR[bi] + ((kc*128 + g*32 + 16) ^ swz)); \
            s16x8 a;                                                           \
            a[0]=f2bf(a0.x); a[1]=f2bf(a0.y); a[2]=f2bf(a0.z); a[3]=f2bf(a0.w); \
            a[4]=f2bf(a1.x); a[5]=f2bf(a1.y); a[6]=f2bf(a1.z); a[7]=f2bf(a1.w); \
            _Pragma("unroll")                                                  \
            for (int nf = 0; nf < 6; nf++) {                                   \
                s16x8 bfr = *(const s16x8*)(wR[bi][nf] + ((kc*64 + g*16) ^ swz)); \
                acc[nf] = MFMA16(a, bfr, acc[nf]);                             \
            }                                                                  \
        } }

    PSTAGE(0, db0);
    PSTAGE(1, db1);

    for (int kk = 0; kk < 15; kk++) {
        asm volatile("s_waitcnt vmcnt(5)" ::: "memory");
        __builtin_amdgcn_sched_barrier(0);
        __builtin_amdgcn_s_barrier();
        if (kk & 1) PCOMPUTE(1) else PCOMPUTE(0)
        asm volatile("s_waitcnt lgkmcnt(0)" ::: "memory");
        __builtin_amdgcn_sched_barrier(0);
        __builtin_amdgcn_s_barrier();
        if (kk < 14) { if (kk & 1) PSTAGE(kk + 2, db1) else PSTAGE(kk + 2, db0) }
    }
    asm volatile("s_waitcnt vmcnt(0)" ::: "memory");
    __builtin_amdgcn_sched_barrier(0);
    __builtin_amdgcn_s_barrier();
    PCOMPUTE(1)
#undef PSTAGE
#undef PCOMPUTE

#pragma unroll
    for (int nf = 0; nf < 6; nf++) {
        int col16 = n0 + nf * 16;
        if (col16 < 64) {
            int col = col16 + c;
#pragma unroll
            for (int r = 0; r < 4; r++)
                Qs[(size_t)(m0 + rg * 16 + g * 4 + r) * 64 + col] = f2bf(acc[nf][r]);
        } else if (col16 < 128) {
            int col = col16 - 64 + c;
#pragma unroll
            for (int r = 0; r < 4; r++)
                Ks[(size_t)(m0 + rg * 16 + g * 4 + r) * 64 + col] = f2bf(acc[nf][r]);
        } else {
            int d  = col16 - 128 + c;
            int mm = m0 + rg * 16 + g * 4;
            int bt = mm >> 12, s0 = mm & (SEQ - 1);
            short4 o;
            o.x = f2bf(acc[nf][0]); o.y = f2bf(acc[nf][1]);
            o.z = f2bf(acc[nf][2]); o.w = f2bf(acc[nf][3]);
            *(short4*)(Vt + ((size_t)(bt * 64 + d)) * SEQ + s0) = o;
        }
    }
}

// ---------------------------------------------------------------------------
// Kernel 2: causal flash attention, swapped-QK 32x32x16, split-K x4 waves,
// with COOPERATIVE LDS STAGING of K/V slabs (128 kv per round):
//   K slab 16KB (rows 128B, chunk^=(row&7)), V slab 16KB (rows 256B,
//   chunk^=(row&15)); both-sides swizzle, linear GLDS dests (rule #21).
// Double-buffered, counted vmcnt(8) (8 GLDS/wave/slab, 2 slabs in flight),
// raw s_barrier. Combine buffers union'd into the slab LDS after the loop.
__global__ __launch_bounds__(256) void k_attn(const short* __restrict__ Qs,
                                              const short* __restrict__ Ks,
                                              const short* __restrict__ Vt,
                                              float* __restrict__ out) {
    __shared__ __align__(16) char smem[65536];   // buf b: K at b*32768, V at +16384
    float (*pO)[64][33] = (float (*)[64][33])smem;          // union (post-loop)
    float* pM = (float*)(smem + 33792);
    float* pL = pM + 128;

    int tid = threadIdx.x;
    int l = tid & 63, wv = tid >> 6;
    int q = l & 31, hi = l >> 5;
    int bid = blockIdx.x;
    int j = 127 - (bid >> 2), bt = bid & 3;   // LPT: heavy tiles first
    int q0 = j * 32;
    const int kend = q0 + 32;
    const int R = (kend + 127) >> 7;          // 128-kv rounds

    const short* Qb = Qs + (size_t)bt * SEQ * 64;
    const short* Kb = Ks + (size_t)bt * SEQ * 64;
    const short* Vb = Vt + (size_t)bt * 64 * SEQ;

    s16x8 qf[4];
#pragma unroll
    for (int d = 0; d < 4; d++)
        qf[d] = *(const s16x8*)(Qb + (size_t)(q0 + q) * 64 + d * 16 + hi * 8);

    // staging lane constants
    const int kr  = l >> 3;                   // K: row sub-idx 0..7
    const int kch = (l & 7) ^ kr;             // K: pre-swizzled source chunk
    const int vr  = l >> 4;                   // V: row sub-idx 0..3

    // wave-uniform LDS dest bases (HW adds lane*16)
#define ASTAGE(kbase, bufb) {                                                  \
        _Pragma("unroll")                                                      \
        for (int i = 0; i < 4; i++)                                            \
            GLDS(Kb + (((size_t)((kbase) + wv*32 + i*8 + kr)) << 6) + kch*8,   \
                 smem + (bufb)*32768 + (wv*4 + i)*1024);                       \
        _Pragma("unroll")                                                      \
        for (int i = 0; i < 4; i++)                                            \
            GLDS(Vb + (size_t)(wv*16 + i*4 + vr) * SEQ + (kbase)               \
                    + (((l & 15) ^ (i*4 + vr)) * 8),                           \
                 smem + (bufb)*32768 + 16384 + (wv*4 + i)*1024); }

    f32x16 o0 = {}, o1 = {};
    float m = -1e30f, ll = 0.f;

    ASTAGE(0, 0);
    ASTAGE(128, 1);

    for (int r = 0; r < R; r++) {
        if (r == R - 1) asm volatile("s_waitcnt vmcnt(0)" ::: "memory");
        else            asm volatile("s_waitcnt vmcnt(8)" ::: "memory");
        __builtin_amdgcn_sched_barrier(0);
        __builtin_amdgcn_s_barrier();
        __builtin_amdgcn_sched_barrier(0);

        int k0 = r * 128 + wv * 32;
        if (k0 < kend) {
            // ---- K A-frags from LDS (chunk = (hi+2d) ^ (q&7)) ----
            const char* kb = smem + (r & 1) * 32768 + (wv * 32 + q) * 128;
            int ks = q & 7;
            s16x8 ka0 = *(const s16x8*)(kb + (((hi    ) ^ ks) << 4));
            s16x8 ka1 = *(const s16x8*)(kb + (((hi + 2) ^ ks) << 4));
            s16x8 ka2 = *(const s16x8*)(kb + (((hi + 4) ^ ks) << 4));
            s16x8 ka3 = *(const s16x8*)(kb + (((hi + 6) ^ ks) << 4));
            f32x16 s = {};
            s = MFMA32(ka0, qf[0], s);
            s = MFMA32(ka1, qf[1], s);
            s = MFMA32(ka2, qf[2], s);
            s = MFMA32(ka3, qf[3], s);

            if (k0 + 31 > q0) {               // causal mask near diagonal
#pragma unroll
                for (int rr = 0; rr < 16; rr++) {
                    int kk = k0 + (rr & 3) + 8 * (rr >> 2) + 4 * hi;
                    if (kk > q0 + q) s[rr] = -3.0e38f;
                }
            }

            // ---- in-register softmax (base-2; scale folded in Wq) ----
            float t0 = fmaxf(fmaxf(fmaxf(s[0], s[1]), fmaxf(s[2], s[3])),
                             fmaxf(fmaxf(s[4], s[5]), fmaxf(s[6], s[7])));
            float t1 = fmaxf(fmaxf(fmaxf(s[8], s[9]), fmaxf(s[10], s[11])),
                             fmaxf(fmaxf(s[12], s[13]), fmaxf(s[14], s[15])));
            float tm = fmaxf(t0, t1);
            u32x2 sw = __builtin_amdgcn_permlane32_swap(fbits(tm), fbits(tm), false, false);
            tm = fmaxf(bitsf(sw[0]), bitsf(sw[1]));
            float mn = fmaxf(m, tm);
            float scale = __builtin_amdgcn_exp2f(m - mn);
            m = mn;
#pragma unroll
            for (int rr = 0; rr < 16; rr++) s[rr] = __builtin_amdgcn_exp2f(s[rr] - mn);
            float u0s = ((s[0] + s[1]) + (s[2] + s[3])) + ((s[4] + s[5]) + (s[6] + s[7]));
            float u1s = ((s[8] + s[9]) + (s[10] + s[11])) + ((s[12] + s[13]) + (s[14] + s[15]));
            float ts = u0s + u1s;
            sw = __builtin_amdgcn_permlane32_swap(fbits(ts), fbits(ts), false, false);
            ts = bitsf(sw[0]) + bitsf(sw[1]);
            ll = ll * scale + ts;
            o0 *= scale; o1 *= scale;

            // ---- P -> bf16 B-frags via pack + permlane32_swap ----
            unsigned A0 = pk2(s[0], s[1]),   B0 = pk2(s[2], s[3]);
            unsigned A1 = pk2(s[4], s[5]),   B1 = pk2(s[6], s[7]);
            unsigned A2 = pk2(s[8], s[9]),   B2 = pk2(s[10], s[11]);
            unsigned A3 = pk2(s[12], s[13]), B3 = pk2(s[14], s[15]);
            u32x2 r0 = __builtin_amdgcn_permlane32_swap(A0, A1, false, false);
            u32x2 r1 = __builtin_amdgcn_permlane32_swap(B0, B1, false, false);
            u32x2 r2 = __builtin_amdgcn_permlane32_swap(A2, A3, false, false);
            u32x2 r3 = __builtin_amdgcn_permlane32_swap(B2, B3, false, false);
            union { unsigned u[4]; s16x8 v; } p0u, p1u;
            p0u.u[0] = r0[0]; p0u.u[1] = r1[0]; p0u.u[2] = r0[1]; p0u.u[3] = r1[1];
            p1u.u[0] = r2[0]; p1u.u[1] = r3[0]; p1u.u[2] = r2[1]; p1u.u[3] = r3[1];

            // ---- O^T += V^T P^T : V A-frags from LDS (chunk^(row&15)) ----
            const char* vbb = smem + (r & 1) * 32768 + 16384;
            int vc0 = ((4 * wv + hi)     ^ (q & 15)) << 4;
            int vc1 = ((4 * wv + hi + 2) ^ (q & 15)) << 4;
            const char* v0p = vbb + q * 256;
            const char* v1p = vbb + (q + 32) * 256;
            o0 = MFMA32(*(const s16x8*)(v0p + vc0), p0u.v, o0);
            o0 = MFMA32(*(const s16x8*)(v0p + vc1), p1u.v, o0);
            o1 = MFMA32(*(const s16x8*)(v1p + vc0), p0u.v, o1);
            o1 = MFMA32(*(const s16x8*)(v1p + vc1), p1u.v, o1);
        }

        asm volatile("s_waitcnt lgkmcnt(0)" ::: "memory");
        __builtin_amdgcn_sched_barrier(0);
        __builtin_amdgcn_s_barrier();
        if (r + 2 < R) { if (r & 1) ASTAGE((r + 2) * 128, 1) else ASTAGE((r + 2) * 128, 0) }
    }
#undef ASTAGE

    // ---- flash-combine across 4 split-K waves (LDS union'd with slabs) ----
#pragma unroll
    for (int rr = 0; rr < 16; rr++) {
        int dv = (rr & 3) + 8 * (rr >> 2) + 4 * hi;
        pO[wv][dv][q]      = o0[rr];
        pO[wv][dv + 32][q] = o1[rr];
    }
    if (hi == 0) { pM[wv * 32 + q] = m; pL[wv * 32 + q] = ll; }
    __syncthreads();

    int q2 = tid >> 3, d0 = (tid & 7) * 8;    // thread -> (q, 8 dv)
    float m0v = pM[q2], m1v = pM[32 + q2], m2v = pM[64 + q2], m3v = pM[96 + q2];
    float M = fmaxf(fmaxf(m0v, m1v), fmaxf(m2v, m3v));
    float w0 = __builtin_amdgcn_exp2f(m0v - M);
    float w1 = __builtin_amdgcn_exp2f(m1v - M);
    float w2 = __builtin_amdgcn_exp2f(m2v - M);
    float w3 = __builtin_amdgcn_exp2f(m3v - M);
    float L = w0 * pL[q2] + w1 * pL[32 + q2] + w2 * pL[64 + q2] + w3 * pL[96 + q2];
    float inv = 1.0f / L;
    float res[8];
#pragma unroll
    for (int i = 0; i < 8; i++)
        res[i] = (w0 * pO[0][d0 + i][q2] + w1 * pO[1][d0 + i][q2]
                + w2 * pO[2][d0 + i][q2] + w3 * pO[3][d0 + i][q2]) * inv;
    float* op = out + ((size_t)bt * SEQ + q0 + q2) * 64 + d0;
    float4 f0 = {res[0], res[1], res[2], res[3]};
    float4 f1 = {res[4], res[5], res[6], res[7]};
    *(float4*)op = f0;
    *(float4*)(op + 4) = f1;
}

// ---------------------------------------------------------------------------
extern "C" void kernel_launch(void* const* d_in, const int* in_sizes, int n_in,
                              void* d_out, int out_size, void* d_ws, size_t ws_size,
                              hipStream_t stream) {
    const float* x  = (const float*)d_in[0];
    const float* Wq = (const float*)d_in[1];
    const float* Wk = (const float*)d_in[2];
    const float* Wv = (const float*)d_in[3];
    float* out = (float*)d_out;

    char* ws = (char*)d_ws;
    short* Wb = (short*)ws;                                   // 384 KB
    short* Qs = (short*)(ws + 393216);                        // 2 MB
    short* Ks = (short*)(ws + 393216 + 2097152);              // 2 MB
    short* Vt = (short*)(ws + 393216 + 2 * 2097152);          // 2 MB  [B][64][S]

    k_convw<<<dim3(192), dim3(256), 0, stream>>>(Wq, Wk, Wv, Wb);
    k_proj <<<dim3(256), dim3(512), 0, stream>>>(x, Wb, Qs, Ks, Vt);
    k_attn <<<dim3(512), dim3(256), 0, stream>>>(Qs, Ks, Vt, out);
}

// Round 7
// 63.104 us; speedup vs baseline: 3.4970x; 1.0676x over previous
//
#include <hip/hip_runtime.h>
#include <hip/hip_bf16.h>

// y = softmax_causal((x Wq^T)(x Wk^T)^T / 8) (x Wv^T)
// B=4, S=4096, D_EMBED=1024, D=64. fp32 in/out; bf16 MFMA compute.

typedef short s16x8 __attribute__((ext_vector_type(8)));
typedef float f32x4 __attribute__((ext_vector_type(4)));
typedef float f32x16 __attribute__((ext_vector_type(16)));
typedef unsigned u32x2 __attribute__((ext_vector_type(2)));

#define MFMA16(a, b, c) __builtin_amdgcn_mfma_f32_16x16x32_bf16(a, b, c, 0, 0, 0)
#define MFMA32(a, b, c) __builtin_amdgcn_mfma_f32_32x32x16_bf16(a, b, c, 0, 0, 0)

constexpr int SEQ = 4096;
constexpr int DE  = 1024;

__device__ __forceinline__ short f2bf(float f) {            // RNE fp32->bf16
    union { float f; unsigned u; } v; v.f = f;
    unsigned r = (v.u + 0x7FFFu + ((v.u >> 16) & 1u)) >> 16;
    return (short)r;
}
__device__ __forceinline__ unsigned fbits(float f) { union { float f; unsigned u; } v; v.f = f; return v.u; }
__device__ __forceinline__ float bitsf(unsigned u) { union { unsigned u; float f; } v; v.u = u; return v.f; }
__device__ __forceinline__ unsigned pk2(float a, float b) {  // 2xf32 -> packed bf16 (trunc)
    return (fbits(b) & 0xFFFF0000u) | (fbits(a) >> 16);
}

#define GLDS(gp, lp)                                                          \
    __builtin_amdgcn_global_load_lds(                                         \
        (const __attribute__((address_space(1))) unsigned int*)(gp),          \
        (__attribute__((address_space(3))) unsigned int*)(lp), 16, 0, 0)

// ---------------------------------------------------------------------------
// Kernel 0: W (fp32 [64][1024] x3) -> bf16 [192][1024]; 0.125*log2e folded in Wq.
__global__ __launch_bounds__(256) void k_convw(const float* __restrict__ Wq,
                                               const float* __restrict__ Wk,
                                               const float* __restrict__ Wv,
                                               short* __restrict__ Wb) {
    int i = (blockIdx.x * 256 + threadIdx.x) * 4;
    if (i >= 192 * 1024) return;
    int n = i >> 10, k = i & 1023;
    const float* src; float sc;
    if (n < 64)       { src = Wq + n * 1024;         sc = 0.18033688011112042f; }
    else if (n < 128) { src = Wk + (n - 64) * 1024;  sc = 1.0f; }
    else              { src = Wv + (n - 128) * 1024; sc = 1.0f; }
    float4 v = *(const float4*)(src + k);
    short4 o;
    o.x = f2bf(v.x * sc); o.y = f2bf(v.y * sc);
    o.z = f2bf(v.z * sc); o.w = f2bf(v.w * sc);
    *(short4*)(Wb + i) = o;
}

// ---------------------------------------------------------------------------
// Kernel 1: QKV projection, counted-vmcnt pipelined GEMM. BM=32 (was 64):
// LDS 2x32KB -> 2 blocks/CU, 16 waves/CU (4/SIMD). 512 blocks x 512 thr.
// Per K-step: A 8KB (1 GLDS/thr) + W 24KB (3 GLDS/thr) -> vmcnt(4).
__global__ __launch_bounds__(512, 4) void k_proj(const float* __restrict__ x,
                                                 const short* __restrict__ Wb,
                                                 short* __restrict__ Qs,
                                                 short* __restrict__ Ks,
                                                 short* __restrict__ Vt) {
    __shared__ __align__(16) char lds[2][32768];   // per buf: A 8KB | W 24KB
    const int tid  = threadIdx.x;
    const int lane = tid & 63;
    const int c = lane & 15, g = (lane >> 4) & 3;
    const int wv = tid >> 6;
    const int rg = wv & 1, nh = wv >> 1;
    const int n0 = nh * 48;
    const int m0 = blockIdx.x * 32;

    const int Ar  = tid >> 4;                                   // A row 0..31
    const int Acs = ((tid & 15) << 4) ^ ((Ar & 7) << 4);
    const char* aS0 = (const char*)x + (((size_t)(m0 + Ar)) << 12) + Acs;
    const int Wr  = tid >> 3;                                   // W row 0..63
    const int Wcs = ((tid & 7) << 4) ^ ((Wr & 7) << 4);
    const char* wS0 = (const char*)Wb + (((size_t)Wr) << 11) + Wcs;
    const char* wS1 = wS0 + ((size_t)64 << 11);
    const char* wS2 = wS0 + ((size_t)128 << 11);

    char* db0 = &lds[0][0] + tid * 16;
    char* db1 = &lds[1][0] + tid * 16;

    const int arow = rg * 16 + c;
    const int swz  = (c & 7) << 4;
    const char* aR[2] = { &lds[0][0] + arow * 256, &lds[1][0] + arow * 256 };
    const char* wR[2][3];
#pragma unroll
    for (int nf = 0; nf < 3; nf++) {
        int wrow = n0 + nf * 16 + c;
        wR[0][nf] = &lds[0][0] + 8192 + wrow * 128;
        wR[1][nf] = &lds[1][0] + 8192 + wrow * 128;
    }

    f32x4 acc[3];
#pragma unroll
    for (int i = 0; i < 3; i++) acc[i] = (f32x4){0.f, 0.f, 0.f, 0.f};

#define PSTAGE(kk, db) {                                  \
        GLDS(aS0 + (kk) * 256, (db));                     \
        GLDS(wS0 + (kk) * 128, (db) + 8192);              \
        GLDS(wS1 + (kk) * 128, (db) + 16384);             \
        GLDS(wS2 + (kk) * 128, (db) + 24576); }

#define PCOMPUTE(bi) {                                                         \
        _Pragma("unroll")                                                      \
        for (int kc = 0; kc < 2; kc++) {                                       \
            float4 a0 = *(const float4*)(aR[bi] + ((kc*128 + g*32)      ^ swz)); \
            float4 a1 = *(const float4*)(aR[bi] + ((kc*128 + g*32 + 16) ^ swz)); \
            s16x8 a;                                                           \
            a[0]=f2bf(a0.x); a[1]=f2bf(a0.y); a[2]=f2bf(a0.z); a[3]=f2bf(a0.w); \
            a[4]=f2bf(a1.x); a[5]=f2bf(a1.y); a[6]=f2bf(a1.z); a[7]=f2bf(a1.w); \
            _Pragma("unroll")                                                  \
            for (int nf = 0; nf < 3; nf++) {                                   \
                s16x8 bfr = *(const s16x8*)(wR[bi][nf] + ((kc*64 + g*16) ^ swz)); \
                acc[nf] = MFMA16(a, bfr, acc[nf]);                             \
            }                                                                  \
        } }

    PSTAGE(0, db0);
    PSTAGE(1, db1);

    for (int kk = 0; kk < 15; kk++) {
        asm volatile("s_waitcnt vmcnt(4)" ::: "memory");
        __builtin_amdgcn_sched_barrier(0);
        __builtin_amdgcn_s_barrier();
        if (kk & 1) PCOMPUTE(1) else PCOMPUTE(0)
        asm volatile("s_waitcnt lgkmcnt(0)" ::: "memory");
        __builtin_amdgcn_sched_barrier(0);
        __builtin_amdgcn_s_barrier();
        if (kk < 14) { if (kk & 1) PSTAGE(kk + 2, db1) else PSTAGE(kk + 2, db0) }
    }
    asm volatile("s_waitcnt vmcnt(0)" ::: "memory");
    __builtin_amdgcn_sched_barrier(0);
    __builtin_amdgcn_s_barrier();
    PCOMPUTE(1)
#undef PSTAGE
#undef PCOMPUTE

#pragma unroll
    for (int nf = 0; nf < 3; nf++) {
        int col16 = n0 + nf * 16;
        if (col16 < 64) {
            int col = col16 + c;
#pragma unroll
            for (int r = 0; r < 4; r++)
                Qs[(size_t)(m0 + rg * 16 + g * 4 + r) * 64 + col] = f2bf(acc[nf][r]);
        } else if (col16 < 128) {
            int col = col16 - 64 + c;
#pragma unroll
            for (int r = 0; r < 4; r++)
                Ks[(size_t)(m0 + rg * 16 + g * 4 + r) * 64 + col] = f2bf(acc[nf][r]);
        } else {
            int d  = col16 - 128 + c;
            int mm = m0 + rg * 16 + g * 4;
            int bt = mm >> 12, s0 = mm & (SEQ - 1);
            short4 o;
            o.x = f2bf(acc[nf][0]); o.y = f2bf(acc[nf][1]);
            o.z = f2bf(acc[nf][2]); o.w = f2bf(acc[nf][3]);
            *(short4*)(Vt + ((size_t)(bt * 64 + d)) * SEQ + s0) = o;
        }
    }
}

// ---------------------------------------------------------------------------
// Kernel 2: flash attention PARTIALS over work units (bt, q-tile j, 1024-kv
// segment). 1280 near-uniform blocks (<=8 rounds), heavy-first, real LPT
// backfill at 2 blocks/CU. Body = R6's staged swapped-QK split-K x4 waves.
// Writes unnormalized partial (O*w, M, L) per unit to ws; k_comb merges.
__global__ __launch_bounds__(256, 2) void k_attn(const short* __restrict__ Qs,
                                                 const short* __restrict__ Ks,
                                                 const short* __restrict__ Vt,
                                                 float* __restrict__ pws) {
    __shared__ __align__(16) char smem[65536];   // buf b: K at b*32768, V at +16384
    float (*pO)[64][33] = (float (*)[64][33])smem;          // union (post-loop)
    float* pM = (float*)(smem + 33792);
    float* pL = pM + 128;

    int tid = threadIdx.x;
    int l = tid & 63, wv = tid >> 6;
    int q = l & 31, hi = l >> 5;

    // unit decode: ub -> (j, seg), 4-seg tiles first (heavy-first dispatch)
    int ub = blockIdx.x >> 2, bt = blockIdx.x & 3;
    int j, seg;
    if (ub < 128)      { j = 127 - (ub >> 2);       seg = ub & 3; }
    else if (ub < 224) { int t = ub - 128; j = 95 - t / 3;  seg = t - (t / 3) * 3; }
    else if (ub < 288) { int t = ub - 224; j = 63 - (t >> 1); seg = t & 1; }
    else               { j = 31 - (ub - 288);       seg = 0; }

    int q0 = j * 32;
    int kbase = seg << 10;
    int kend_u = min(q0 + 32, kbase + 1024);
    const int R = (kend_u - kbase + 127) >> 7;

    const short* Qb = Qs + (size_t)bt * SEQ * 64;
    const short* Kb = Ks + (size_t)bt * SEQ * 64;
    const short* Vb = Vt + (size_t)bt * 64 * SEQ;

    s16x8 qf[4];
#pragma unroll
    for (int d = 0; d < 4; d++)
        qf[d] = *(const s16x8*)(Qb + (size_t)(q0 + q) * 64 + d * 16 + hi * 8);

    const int kr  = l >> 3;                   // K staging: row sub-idx 0..7
    const int kch = (l & 7) ^ kr;             // pre-swizzled source chunk
    const int vr  = l >> 4;                   // V staging: row sub-idx 0..3

#define ASTAGE(kb2, bufb) {                                                    \
        _Pragma("unroll")                                                      \
        for (int i = 0; i < 4; i++)                                            \
            GLDS(Kb + (((size_t)((kb2) + wv*32 + i*8 + kr)) << 6) + kch*8,     \
                 smem + (bufb)*32768 + (wv*4 + i)*1024);                       \
        _Pragma("unroll")                                                      \
        for (int i = 0; i < 4; i++)                                            \
            GLDS(Vb + (size_t)(wv*16 + i*4 + vr) * SEQ + (kb2)                 \
                    + (((l & 15) ^ (i*4 + vr)) * 8),                           \
                 smem + (bufb)*32768 + 16384 + (wv*4 + i)*1024); }

    f32x16 o0 = {}, o1 = {};
    float m = -1e30f, ll = 0.f;

    ASTAGE(kbase, 0);
    ASTAGE(kbase + 128, 1);

    for (int r = 0; r < R; r++) {
        if (r == R - 1) asm volatile("s_waitcnt vmcnt(0)" ::: "memory");
        else            asm volatile("s_waitcnt vmcnt(8)" ::: "memory");
        __builtin_amdgcn_sched_barrier(0);
        __builtin_amdgcn_s_barrier();
        __builtin_amdgcn_sched_barrier(0);

        int k0 = kbase + r * 128 + wv * 32;
        if (k0 < kend_u) {
            const char* kb = smem + (r & 1) * 32768 + (wv * 32 + q) * 128;
            int ks = q & 7;
            s16x8 ka0 = *(const s16x8*)(kb + (((hi    ) ^ ks) << 4));
            s16x8 ka1 = *(const s16x8*)(kb + (((hi + 2) ^ ks) << 4));
            s16x8 ka2 = *(const s16x8*)(kb + (((hi + 4) ^ ks) << 4));
            s16x8 ka3 = *(const s16x8*)(kb + (((hi + 6) ^ ks) << 4));
            f32x16 s = {};
            s = MFMA32(ka0, qf[0], s);
            s = MFMA32(ka1, qf[1], s);
            s = MFMA32(ka2, qf[2], s);
            s = MFMA32(ka3, qf[3], s);

            if (k0 + 31 > q0) {               // causal mask near diagonal
#pragma unroll
                for (int rr = 0; rr < 16; rr++) {
                    int kk = k0 + (rr & 3) + 8 * (rr >> 2) + 4 * hi;
                    if (kk > q0 + q) s[rr] = -3.0e38f;
                }
            }

            float t0 = fmaxf(fmaxf(fmaxf(s[0], s[1]), fmaxf(s[2], s[3])),
                             fmaxf(fmaxf(s[4], s[5]), fmaxf(s[6], s[7])));
            float t1 = fmaxf(fmaxf(fmaxf(s[8], s[9]), fmaxf(s[10], s[11])),
                             fmaxf(fmaxf(s[12], s[13]), fmaxf(s[14], s[15])));
            float tm = fmaxf(t0, t1);
            u32x2 sw = __builtin_amdgcn_permlane32_swap(fbits(tm), fbits(tm), false, false);
            tm = fmaxf(bitsf(sw[0]), bitsf(sw[1]));
            float mn = fmaxf(m, tm);
            float scale = __builtin_amdgcn_exp2f(m - mn);
            m = mn;
#pragma unroll
            for (int rr = 0; rr < 16; rr++) s[rr] = __builtin_amdgcn_exp2f(s[rr] - mn);
            float u0s = ((s[0] + s[1]) + (s[2] + s[3])) + ((s[4] + s[5]) + (s[6] + s[7]));
            float u1s = ((s[8] + s[9]) + (s[10] + s[11])) + ((s[12] + s[13]) + (s[14] + s[15]));
            float ts = u0s + u1s;
            sw = __builtin_amdgcn_permlane32_swap(fbits(ts), fbits(ts), false, false);
            ts = bitsf(sw[0]) + bitsf(sw[1]);
            ll = ll * scale + ts;
            o0 *= scale; o1 *= scale;

            unsigned A0 = pk2(s[0], s[1]),   B0 = pk2(s[2], s[3]);
            unsigned A1 = pk2(s[4], s[5]),   B1 = pk2(s[6], s[7]);
            unsigned A2 = pk2(s[8], s[9]),   B2 = pk2(s[10], s[11]);
            unsigned A3 = pk2(s[12], s[13]), B3 = pk2(s[14], s[15]);
            u32x2 r0 = __builtin_amdgcn_permlane32_swap(A0, A1, false, false);
            u32x2 r1 = __builtin_amdgcn_permlane32_swap(B0, B1, false, false);
            u32x2 r2 = __builtin_amdgcn_permlane32_swap(A2, A3, false, false);
            u32x2 r3 = __builtin_amdgcn_permlane32_swap(B2, B3, false, false);
            union { unsigned u[4]; s16x8 v; } p0u, p1u;
            p0u.u[0] = r0[0]; p0u.u[1] = r1[0]; p0u.u[2] = r0[1]; p0u.u[3] = r1[1];
            p1u.u[0] = r2[0]; p1u.u[1] = r3[0]; p1u.u[2] = r2[1]; p1u.u[3] = r3[1];

            const char* vbb = smem + (r & 1) * 32768 + 16384;
            int vc0 = ((4 * wv + hi)     ^ (q & 15)) << 4;
            int vc1 = ((4 * wv + hi + 2) ^ (q & 15)) << 4;
            const char* v0p = vbb + q * 256;
            const char* v1p = vbb + (q + 32) * 256;
            o0 = MFMA32(*(const s16x8*)(v0p + vc0), p0u.v, o0);
            o0 = MFMA32(*(const s16x8*)(v0p + vc1), p1u.v, o0);
            o1 = MFMA32(*(const s16x8*)(v1p + vc0), p0u.v, o1);
            o1 = MFMA32(*(const s16x8*)(v1p + vc1), p1u.v, o1);
        }

        asm volatile("s_waitcnt lgkmcnt(0)" ::: "memory");
        __builtin_amdgcn_sched_barrier(0);
        __builtin_amdgcn_s_barrier();
        if (r + 2 < R) { if (r & 1) ASTAGE(kbase + (r + 2) * 128, 1) else ASTAGE(kbase + (r + 2) * 128, 0) }
    }
#undef ASTAGE

    // ---- block combine of 4 split-K waves -> unnormalized partial to ws ----
#pragma unroll
    for (int rr = 0; rr < 16; rr++) {
        int dv = (rr & 3) + 8 * (rr >> 2) + 4 * hi;
        pO[wv][dv][q]      = o0[rr];
        pO[wv][dv + 32][q] = o1[rr];
    }
    if (hi == 0) { pM[wv * 32 + q] = m; pL[wv * 32 + q] = ll; }
    __syncthreads();

    int q2 = tid >> 3, d0 = (tid & 7) * 8;
    float m0v = pM[q2], m1v = pM[32 + q2], m2v = pM[64 + q2], m3v = pM[96 + q2];
    float M = fmaxf(fmaxf(m0v, m1v), fmaxf(m2v, m3v));
    float w0 = __builtin_amdgcn_exp2f(m0v - M);
    float w1 = __builtin_amdgcn_exp2f(m1v - M);
    float w2 = __builtin_amdgcn_exp2f(m2v - M);
    float w3 = __builtin_amdgcn_exp2f(m3v - M);
    float L = w0 * pL[q2] + w1 * pL[32 + q2] + w2 * pL[64 + q2] + w3 * pL[96 + q2];
    float res[8];
#pragma unroll
    for (int i = 0; i < 8; i++)
        res[i] = w0 * pO[0][d0 + i][q2] + w1 * pO[1][d0 + i][q2]
               + w2 * pO[2][d0 + i][q2] + w3 * pO[3][d0 + i][q2];
    float* p = pws + (size_t)(((bt << 7) + j) * 4 + seg) * 2112;
    float4 f0 = {res[0], res[1], res[2], res[3]};
    float4 f1 = {res[4], res[5], res[6], res[7]};
    *(float4*)(p + q2 * 64 + d0) = f0;
    *(float4*)(p + q2 * 64 + d0 + 4) = f1;
    if ((tid & 7) == 0) { p[2048 + q2] = M; p[2080 + q2] = L; }
}

// ---------------------------------------------------------------------------
// Kernel 3: merge <=4 segment partials per (bt, j) tile -> fp32 out.
__global__ __launch_bounds__(256) void k_comb(const float* __restrict__ pws,
                                              float* __restrict__ out) {
    int bid = blockIdx.x;                 // bt*128 + j
    int bt = bid >> 7, j = bid & 127;
    int nseg = (j >> 5) + 1;
    int tid = threadIdx.x;
    int q2 = tid >> 3, d0 = (tid & 7) * 8;
    const float* base = pws + (size_t)(bid * 4) * 2112;

    float ms[4], wsg[4];
    float M = -1e30f;
#pragma unroll 4
    for (int s = 0; s < nseg; s++) { ms[s] = base[s * 2112 + 2048 + q2]; M = fmaxf(M, ms[s]); }
    float L = 0.f;
#pragma unroll 4
    for (int s = 0; s < nseg; s++) {
        wsg[s] = __builtin_amdgcn_exp2f(ms[s] - M);
        L += wsg[s] * base[s * 2112 + 2080 + q2];
    }
    float inv = 1.0f / L;
    float res[8];
#pragma unroll
    for (int i = 0; i < 8; i++) res[i] = 0.f;
#pragma unroll 4
    for (int s = 0; s < nseg; s++) {
        const float* po = base + s * 2112 + q2 * 64 + d0;
#pragma unroll
        for (int i = 0; i < 8; i++) res[i] += wsg[s] * po[i];
    }
    float* op = out + ((size_t)bt * SEQ + j * 32 + q2) * 64 + d0;
    float4 f0 = {res[0] * inv, res[1] * inv, res[2] * inv, res[3] * inv};
    float4 f1 = {res[4] * inv, res[5] * inv, res[6] * inv, res[7] * inv};
    *(float4*)op = f0;
    *(float4*)(op + 4) = f1;
}

// ---------------------------------------------------------------------------
extern "C" void kernel_launch(void* const* d_in, const int* in_sizes, int n_in,
                              void* d_out, int out_size, void* d_ws, size_t ws_size,
                              hipStream_t stream) {
    const float* x  = (const float*)d_in[0];
    const float* Wq = (const float*)d_in[1];
    const float* Wk = (const float*)d_in[2];
    const float* Wv = (const float*)d_in[3];
    float* out = (float*)d_out;

    char* ws = (char*)d_ws;
    short* Wb = (short*)ws;                                   // 384 KB
    short* Qs = (short*)(ws + 393216);                        // 2 MB
    short* Ks = (short*)(ws + 393216 + 2097152);              // 2 MB
    short* Vt = (short*)(ws + 393216 + 2 * 2097152);          // 2 MB  [B][64][S]
    float* pP = (float*)(ws + 6684672);                       // partials ~17.3 MB

    k_convw<<<dim3(192),  dim3(256), 0, stream>>>(Wq, Wk, Wv, Wb);
    k_proj <<<dim3(512),  dim3(512), 0, stream>>>(x, Wb, Qs, Ks, Vt);
    k_attn <<<dim3(1280), dim3(256), 0, stream>>>(Qs, Ks, Vt, pP);
    k_comb <<<dim3(512),  dim3(256), 0, stream>>>(pP, out);
}